// Round 4
// baseline (470.039 us; speedup 1.0000x reference)
//
#include <hip/hip_runtime.h>
#include <stdint.h>

typedef __attribute__((ext_vector_type(2))) float f32x2;
typedef __attribute__((ext_vector_type(4))) float f32x4;
typedef __attribute__((ext_vector_type(8))) short s16x8;

static __device__ __forceinline__ unsigned short f2bf(float f) {
  union { float f; uint32_t u; } v; v.f = f;
  uint32_t u = v.u;
  u += 0x7fffu + ((u >> 16) & 1u);   // round-to-nearest-even bf16
  return (unsigned short)(u >> 16);
}

// mode: 0 none, 1 multiply, 2 multiply-by-safe-reciprocal
static __device__ __forceinline__ float dval(const float* dv, long r, long dstr, int mode) {
  if (!dv || mode == 0) return 1.f;
  float d = dv[r * dstr];
  if (mode == 2) return (d != 0.f) ? 1.f / d : 0.f;
  return d;
}

// ---------------- shared transpose tile helper: src f32 [n][32] -> dst bf16 [32][ldn] ----------------
// self-zero-pads dst cols [n, tiles*64) up to ldn.
static __device__ void tpose_tile(const float* __restrict__ src, int n,
                                  const float* __restrict__ dv, long dstr, int mode,
                                  unsigned short* __restrict__ dst, int ldn, int tile,
                                  unsigned short (*sm)[72]) {
  const int t = threadIdx.x;
  const int r0 = tile * 64;
  {
    const int rr = t & 63;
    const int cg = t >> 6;      // 0..3 -> cols cg*8 .. cg*8+7
    const int gr = r0 + rr;
    float sc = 1.f;
    f32x4 v0 = {0.f, 0.f, 0.f, 0.f}, v1 = {0.f, 0.f, 0.f, 0.f};
    if (gr < n) {
      sc = dval(dv, gr, dstr, mode);
      const float* sp = src + (long)gr * 32 + cg * 8;
      v0 = *(const f32x4*)sp;
      v1 = *(const f32x4*)(sp + 4);
    }
#pragma unroll
    for (int j = 0; j < 4; ++j) {
      sm[cg * 8 + j][rr] = f2bf(v0[j] * sc);
      sm[cg * 8 + 4 + j][rr] = f2bf(v1[j] * sc);
    }
  }
  __syncthreads();
  {
    const int f = t >> 3;
    const int nc = (t & 7) * 8;
    if (r0 + nc < ldn) {
      s16x8 v = *(const s16x8*)&sm[f][nc];
      *(s16x8*)(dst + (size_t)f * ldn + r0 + nc) = v;
    }
  }
}

// standalone: up to two panels (blockIdx.y selects)
__global__ __launch_bounds__(256) void transpose32_k(
    const float* __restrict__ sA, unsigned short* __restrict__ dA,
    const float* __restrict__ sB, unsigned short* __restrict__ dB,
    int n, int ldn) {
  __shared__ unsigned short sm[32][72];
  const float* s = blockIdx.y ? sB : sA;
  unsigned short* d = blockIdx.y ? dB : dA;
  tpose_tile(s, n, nullptr, 0, 0, d, ldn, blockIdx.x, sm);
}

// ---------------- prep: 6 input transposes + 3 W packs + zero row panels + pad ----------------
__global__ __launch_bounds__(256) void prep(
    const float* __restrict__ x0, const float* __restrict__ x1, const float* __restrict__ x2,
    const float* __restrict__ D1, const float* __restrict__ D3, const float* __restrict__ D5,
    const float* __restrict__ W0, const float* __restrict__ W1, const float* __restrict__ W2,
    unsigned short* x0T, unsigned short* x0dT, unsigned short* x1T,
    unsigned short* x1dT, unsigned short* x2dT, unsigned short* x2T,
    unsigned short* W0T, unsigned short* W1T, unsigned short* W2T,
    float* zero_base, long zero_n, unsigned short* x1nT_pad) {
  __shared__ unsigned short sm[32][72];
  int b = blockIdx.x;
  if (b < 24) { tpose_tile(x0, 1500, nullptr, 0, 0, x0T, 1504, b, sm); return; }
  b -= 24;
  if (b < 24) { tpose_tile(x0, 1500, D1, 1501, 2, x0dT, 1504, b, sm); return; }
  b -= 24;
  if (b < 94) { tpose_tile(x1, 6000, nullptr, 0, 0, x1T, 6016, b, sm); return; }
  b -= 94;
  if (b < 94) { tpose_tile(x1, 6000, D5, 6001, 2, x1dT, 6016, b, sm); return; }
  b -= 94;
  if (b < 63) { tpose_tile(x2, 4000, D3, 4001, 1, x2dT, 4000, b, sm); return; }
  b -= 63;
  if (b < 63) { tpose_tile(x2, 4000, nullptr, 0, 0, x2T, 4000, b, sm); return; }
  b -= 63;
  if (b < 3) {
    const float* W = (b == 0) ? W0 : ((b == 1) ? W1 : W2);
    unsigned short* dst = (b == 0) ? W0T : ((b == 1) ? W1T : W2T);
    const int K = (b == 1) ? 11 : 6;
    const int C = K * 32;
    for (int idx = threadIdx.x; idx < 32 * C; idx += 256) {
      int o = idx / C, j = idx - o * C;
      int k = j >> 5, i = j & 31;
      dst[(size_t)o * C + j] = f2bf(W[((long)i * 32 + o) * K + k]);
    }
    return;
  }
  b -= 3;
  {
    long nv = zero_n >> 2;
    f32x4 z = {0.f, 0.f, 0.f, 0.f};
    for (long i = (long)b * 256 + threadIdx.x; i < nv; i += 16L * 256)
      ((f32x4*)zero_base)[i] = z;
    if (b == 0) {
      for (int i = threadIdx.x; i < 32 * 16; i += 256)
        x1nT_pad[(size_t)(i >> 4) * 6016 + 6000 + (i & 15)] = 0;
    }
  }
}

// ---------------- transpose + f32->bf16: out(nO x ldo) = in^T (from round 1/3, proven) ----------------
__global__ __launch_bounds__(256) void convT(
    const float* __restrict__ in, int ldi, int nI, int nC,
    unsigned short* __restrict__ outT, int ldoT) {
  __shared__ unsigned short sT[64][72];
  const int t = threadIdx.x;
  const int tc0 = blockIdx.x * 64;
  const int tr0 = blockIdx.y * 64;
  const int c0 = (t & 15) * 4;
  const int r0 = (t >> 4) * 4;
  unsigned short ub[4][4];
#pragma unroll
  for (int j = 0; j < 4; ++j) {
    int gr = tr0 + r0 + j;
    f32x4 v = {0.f, 0.f, 0.f, 0.f};
    if (gr < nI) {
      const float* pI = in + (size_t)gr * ldi + tc0 + c0;
      if (tc0 + c0 + 3 < nC) {
        v = *(const f32x4*)pI;
      } else {
#pragma unroll
        for (int jj = 0; jj < 4; ++jj) if (tc0 + c0 + jj < nC) v[jj] = pI[jj];
      }
    }
#pragma unroll
    for (int jj = 0; jj < 4; ++jj) ub[j][jj] = f2bf(v[jj]);
  }
#pragma unroll
  for (int jj = 0; jj < 4; ++jj) {
    union { unsigned short u[4]; unsigned long long ll; } w;
#pragma unroll
    for (int j = 0; j < 4; ++j) w.u[j] = ub[j][jj];
    *(unsigned long long*)&sT[c0 + jj][r0] = w.ll;
  }
  __syncthreads();
#pragma unroll
  for (int p = 0; p < 2; ++p) {
    int orow = (t >> 3) + p * 32;
    int rcol = (t & 7) * 8;
    int grow = tc0 + orow;
    int gcol = tr0 + rcol;
    if (grow < nC && gcol < ldoT) {
      union { unsigned long long ll[2]; s16x8 v; } w;
      w.ll[0] = *(const unsigned long long*)&sT[orow][rcol];
      w.ll[1] = *(const unsigned long long*)&sT[orow][rcol + 4];
      *(s16x8*)(outT + (size_t)grow * ldoT + gcol) = w.v;
    }
  }
}

// ---------------- gemm16: C[n_rows][F] (+)= alpha*A@B (+ beta*S), B given as X^T bf16 panels ----------------
// M-tile 16, 4 waves split K in-block, no LDS staging; LDS only for cross-wave reduce.
// AMODE: 0 = f32 row-major, 1 = bf16 row-major (padded), 2 = list of [n][32] f32 panels per k-step.
struct PList { const void* p[12]; };

template <int F, int AMODE, bool RELU>
__global__ __launch_bounds__(256) void gemm16(
    PList AL, long lda, int n_rows, int n_k,
    const unsigned short* __restrict__ Bt0, const unsigned short* __restrict__ Bt1, int ldb,
    float alpha, const float* __restrict__ S0, const float* __restrict__ S1, float beta,
    const float* __restrict__ sv, long sstr, int smode,
    float* __restrict__ C0, float* __restrict__ C1,
    unsigned short* __restrict__ XT0, unsigned short* __restrict__ XT1, int ldxt) {
  constexpr int NT = F / 16;
  constexpr int LDP = F + 4;
  __shared__ float red[4 * 16 * LDP];

  const int tid = threadIdx.x;
  const int w = tid >> 6;
  const int lane = tid & 63;
  const int r = lane & 15;
  const int g = lane >> 4;

  const int nst = (n_k + 31) >> 5;
  const int cpb = (nst + gridDim.y - 1) / gridDim.y;
  const int sb = blockIdx.y * cpb;
  const int se = min(nst, sb + cpb);
  const int q = (se - sb + 3) >> 2;
  const int s0 = sb + w * q;
  const int s1 = min(se, s0 + q);

  const int row = blockIdx.x * 16 + r;
  const bool rowok = row < n_rows;
  const long rowc = rowok ? row : 0;

  const float* Af = nullptr;
  const unsigned short* Ab = nullptr;
  if constexpr (AMODE == 0) Af = (const float*)AL.p[0] + rowc * lda;
  if constexpr (AMODE == 1) Ab = (const unsigned short*)AL.p[0] + rowc * lda;

  const unsigned short* bb[NT];
#pragma unroll
  for (int nt = 0; nt < NT; ++nt) {
    const unsigned short* base = (nt < 2) ? Bt0 : Bt1;
    bb[nt] = base + (size_t)(((nt & 1) << 4) + r) * ldb;
  }

  auto loadA = [&](int s, s16x8& av) {
    const int k0 = s * 32 + g * 8;
    if constexpr (AMODE == 1) {
      av = rowok ? *(const s16x8*)(Ab + k0) : (s16x8)0;
    } else {
      float tmp[8];
      const float* ap;
      if constexpr (AMODE == 2) {
        int su = __builtin_amdgcn_readfirstlane(s);
        ap = (const float*)AL.p[su] + rowc * 32 + g * 8;
      } else {
        ap = Af + k0;
      }
      const bool full = (AMODE == 2) || (k0 + 8 <= n_k);
      if (rowok && full) {
        f32x4 u0 = *(const f32x4*)ap;
        f32x4 u1 = *(const f32x4*)(ap + 4);
#pragma unroll
        for (int j = 0; j < 4; ++j) { tmp[j] = u0[j]; tmp[4 + j] = u1[j]; }
      } else {
#pragma unroll
        for (int j = 0; j < 8; ++j) tmp[j] = (rowok && (k0 + j < n_k)) ? ap[j] : 0.f;
      }
      s16x8 t;
#pragma unroll
      for (int j = 0; j < 8; ++j) t[j] = (short)f2bf(tmp[j]);
      av = t;
    }
  };
  auto loadB = [&](int s, s16x8* bv) {
    const int k0 = s * 32 + g * 8;
#pragma unroll
    for (int nt = 0; nt < NT; ++nt) bv[nt] = *(const s16x8*)(bb[nt] + k0);
  };

  f32x4 acc[NT];
#pragma unroll
  for (int i = 0; i < NT; ++i) acc[i] = f32x4{0.f, 0.f, 0.f, 0.f};

  s16x8 aC = (s16x8)0, aN = (s16x8)0;
  s16x8 bC[NT], bN[NT];
#pragma unroll
  for (int i = 0; i < NT; ++i) { bC[i] = (s16x8)0; bN[i] = (s16x8)0; }

  if (s0 < s1) { loadA(s0, aC); loadB(s0, bC); }
  for (int s = s0; s < s1; ++s) {
    if (s + 1 < s1) { loadA(s + 1, aN); loadB(s + 1, bN); }
#pragma unroll
    for (int nt = 0; nt < NT; ++nt)
      acc[nt] = __builtin_amdgcn_mfma_f32_16x16x32_bf16(aC, bC[nt], acc[nt], 0, 0, 0);
    aC = aN;
#pragma unroll
    for (int nt = 0; nt < NT; ++nt) bC[nt] = bN[nt];
  }

  // cross-wave reduce via LDS: red[w][m][col], m = g*4+j, col = nt*16+r
#pragma unroll
  for (int nt = 0; nt < NT; ++nt)
#pragma unroll
    for (int j = 0; j < 4; ++j)
      red[(w * 16 + g * 4 + j) * LDP + nt * 16 + r] = acc[nt][j];
  __syncthreads();

  const long mg_base = (long)blockIdx.x * 16;

  // phase A: row-major f32 outputs
  {
    const int m = tid >> 4;
    const int cw = tid & 15;
    const long mg = mg_base + m;
    if (mg < n_rows) {
      const float svv = dval(sv, mg, sstr, smode);
      if constexpr (F == 64) {
        const int c0 = cw * 4;
        f32x4 sum = f32x4{0.f, 0.f, 0.f, 0.f};
#pragma unroll
        for (int ww = 0; ww < 4; ++ww) sum += *(const f32x4*)&red[(ww * 16 + m) * LDP + c0];
        float* C = (c0 < 32) ? C0 : C1;
        const float* S = (c0 < 32) ? S0 : S1;
        const int cc = c0 & 31;
        if (gridDim.y > 1) {
#pragma unroll
          for (int j = 0; j < 4; ++j) {
            float v = alpha * sum[j] * svv;
            if (blockIdx.y == 0 && S) v += beta * S[mg * 32 + cc + j];
            atomicAdd(&C[mg * 32 + cc + j], v);
          }
        } else {
          f32x4 v;
#pragma unroll
          for (int j = 0; j < 4; ++j) {
            float x = alpha * sum[j] * svv;
            if (S) x += beta * S[mg * 32 + cc + j];
            if (RELU) x = fmaxf(x, 0.f);
            v[j] = x;
          }
          *(f32x4*)&C[mg * 32 + cc] = v;
        }
      } else {
        const int c0 = cw * 2;
        f32x2 sum = f32x2{0.f, 0.f};
#pragma unroll
        for (int ww = 0; ww < 4; ++ww) sum += *(const f32x2*)&red[(ww * 16 + m) * LDP + c0];
        if (gridDim.y > 1) {
#pragma unroll
          for (int j = 0; j < 2; ++j) {
            float v = alpha * sum[j] * svv;
            if (blockIdx.y == 0 && S0) v += beta * S0[mg * 32 + c0 + j];
            atomicAdd(&C0[mg * 32 + c0 + j], v);
          }
        } else {
          f32x2 v;
#pragma unroll
          for (int j = 0; j < 2; ++j) {
            float x = alpha * sum[j] * svv;
            if (S0) x += beta * S0[mg * 32 + c0 + j];
            if (RELU) x = fmaxf(x, 0.f);
            v[j] = x;
          }
          *(f32x2*)&C0[mg * 32 + c0] = v;
        }
      }
    }
  }

  // phase B: transposed bf16 outputs (only y==1 launches pass XT)
  if (XT0) {
    if constexpr (F == 64) {
      const int c = tid >> 2;
      const int m0 = (tid & 3) * 4;
      union { unsigned short u[4]; unsigned long long ll; } pk;
      bool ok = (mg_base + m0 + 4) <= n_rows;
#pragma unroll
      for (int i = 0; i < 4; ++i) {
        long node = mg_base + m0 + i;
        float sum = 0.f;
#pragma unroll
        for (int ww = 0; ww < 4; ++ww) sum += red[(ww * 16 + m0 + i) * LDP + c];
        float sc = (node < n_rows) ? dval(sv, node, sstr, smode) : 0.f;
        pk.u[i] = f2bf(alpha * sum * sc);
      }
      unsigned short* X = (c < 32) ? XT0 : XT1;
      if (ok) {
        *(unsigned long long*)(X + (size_t)(c & 31) * ldxt + mg_base + m0) = pk.ll;
      } else {
#pragma unroll
        for (int i = 0; i < 4; ++i)
          if (mg_base + m0 + i < n_rows) X[(size_t)(c & 31) * ldxt + mg_base + m0 + i] = pk.u[i];
      }
    } else {
      const int c = tid >> 3;
      const int m0 = (tid & 7) * 2;
      union { unsigned short u[2]; unsigned int ui; } pk;
      bool ok = (mg_base + m0 + 2) <= n_rows;
#pragma unroll
      for (int i = 0; i < 2; ++i) {
        long node = mg_base + m0 + i;
        float sum = 0.f;
#pragma unroll
        for (int ww = 0; ww < 4; ++ww) sum += red[(ww * 16 + m0 + i) * LDP + c];
        float sc = (node < n_rows) ? dval(sv, node, sstr, smode) : 0.f;
        pk.u[i] = f2bf(alpha * sum * sc);
      }
      if (ok) {
        *(unsigned int*)(XT0 + (size_t)c * ldxt + mg_base + m0) = pk.ui;
      } else {
#pragma unroll
        for (int i = 0; i < 2; ++i)
          if (mg_base + m0 + i < n_rows) XT0[(size_t)c * ldxt + mg_base + m0 + i] = pk.u[i];
      }
    }
  }
}

// ---------------- fallback helpers (used only if ws too small for B1t/B2t) ----------------
__global__ void colcopy(float* __restrict__ dst, const float* __restrict__ src, int n,
                        const float* __restrict__ dv, long dstr, int mode) {
  int idx = blockIdx.x * 256 + threadIdx.x;
  if (idx >= n * 32) return;
  dst[idx] = src[idx] * dval(dv, idx >> 5, dstr, mode);
}
__global__ void scale_ip(float* __restrict__ dst, int n,
                         const float* __restrict__ dv, long dstr, int mode) {
  int idx = blockIdx.x * 256 + threadIdx.x;
  if (idx >= n * 32) return;
  dst[idx] *= dval(dv, idx >> 5, dstr, mode);
}
__global__ __launch_bounds__(256) void mm_at(
    const float* __restrict__ A, int lda, int m,
    const float* __restrict__ X,
    float* __restrict__ C, int ldc, int n, int kchunk) {
  const int fg = threadIdx.x & 3;
  const int cg = threadIdx.x >> 2;
  const int c = blockIdx.x * 256 + cg * 4;
  const int k0 = blockIdx.y * kchunk;
  const int k1 = min(m, k0 + kchunk);
  const int f = fg * 8;
  float acc[4][8];
#pragma unroll
  for (int a = 0; a < 4; ++a)
#pragma unroll
    for (int b = 0; b < 8; ++b) acc[a][b] = 0.f;
  for (int k = k0; k < k1; ++k) {
    const float* Ar = A + (size_t)k * lda + c;
    f32x4 a;
    if (c + 3 < n) a = *(const f32x4*)Ar;
    else {
      a = f32x4{0.f, 0.f, 0.f, 0.f};
#pragma unroll
      for (int j = 0; j < 4; ++j) if (c + j < n) a[j] = Ar[j];
    }
    f32x4 xa = *(const f32x4*)(X + (size_t)k * 32 + f);
    f32x4 xb = *(const f32x4*)(X + (size_t)k * 32 + f + 4);
#pragma unroll
    for (int cc = 0; cc < 4; ++cc)
#pragma unroll
      for (int jj = 0; jj < 4; ++jj) {
        acc[cc][jj] += a[cc] * xa[jj];
        acc[cc][4 + jj] += a[cc] * xb[jj];
      }
  }
  if (c >= n) return;
#pragma unroll
  for (int cc = 0; cc < 4; ++cc) {
    if (c + cc >= n) break;
#pragma unroll
    for (int jj = 0; jj < 8; ++jj)
      atomicAdd(&C[(size_t)(c + cc) * ldc + f + jj], acc[cc][jj]);
  }
}

// ---------------- host ----------------

extern "C" void kernel_launch(void* const* d_in, const int* in_sizes, int n_in,
                              void* d_out, int out_size, void* d_ws, size_t ws_size,
                              hipStream_t stream) {
  (void)in_sizes; (void)n_in; (void)out_size;
  const float* x0  = (const float*)d_in[0];
  const float* x1  = (const float*)d_in[1];
  const float* x2  = (const float*)d_in[2];
  const float* B1  = (const float*)d_in[3];
  const float* B2  = (const float*)d_in[4];
  const float* L0  = (const float*)d_in[5];
  const float* L1l = (const float*)d_in[6];
  const float* L1u = (const float*)d_in[7];
  const float* L2  = (const float*)d_in[8];
  const float* D1  = (const float*)d_in[9];
  const float* D2  = (const float*)d_in[10];
  const float* D3  = (const float*)d_in[11];
  const float* D5  = (const float*)d_in[12];
  const float* W0  = (const float*)d_in[13];
  const float* W1  = (const float*)d_in[14];
  const float* W2  = (const float*)d_in[15];
  float* out = (float*)d_out;

  char* p = (char*)d_ws;
  auto alloc = [&](size_t b) { char* r = p; p += (b + 255) & ~(size_t)255; return r; };
  typedef unsigned short us;

  // input transposes (bf16 [32][ldn])
  us* x0T  = (us*)alloc((size_t)32 * 1504 * 2);
  us* x0dT = (us*)alloc((size_t)32 * 1504 * 2);
  us* x1T  = (us*)alloc((size_t)32 * 6016 * 2);
  us* x1dT = (us*)alloc((size_t)32 * 6016 * 2);
  us* x2dT = (us*)alloc((size_t)32 * 4000 * 2);
  us* x2T  = (us*)alloc((size_t)32 * 4000 * 2);
  us* W0T  = (us*)alloc((size_t)32 * 192 * 2);
  us* W1T  = (us*)alloc((size_t)32 * 352 * 2);
  us* W2T  = (us*)alloc((size_t)32 * 192 * 2);

  // row-major f32 panels, one contiguous zero-region
  const long ZROWS = 5L * 1500 + 10L * 6000 + 5L * 4000;  // 87500 rows
  float* ROWS = (float*)alloc((size_t)ZROWS * 32 * 4);
  long ro = 0;
  auto rp = [&](int n) { float* q = ROWS + ro * 32; ro += n; return q; };
  float* r_x0p  = rp(1500); float* r_T1a0 = rp(1500); float* r_T1b0 = rp(1500);
  float* r_T2a0 = rp(1500); float* r_T2b0 = rp(1500);
  float* r_x1n  = rp(6000); float* r_x1p  = rp(6000);
  float* r_T1la = rp(6000); float* r_T1lb = rp(6000);
  float* r_T2la = rp(6000); float* r_T2lb = rp(6000);
  float* r_T1ua = rp(6000); float* r_T1ub = rp(6000);
  float* r_T2ua = rp(6000); float* r_T2ub = rp(6000);
  float* r_x2n  = rp(4000); float* r_T1a2 = rp(4000); float* r_T1b2 = rp(4000);
  float* r_T2a2 = rp(4000); float* r_T2b2 = rp(4000);

  // GEMM-written transposed bf16 panels
  us* x0pT  = (us*)alloc((size_t)32 * 1504 * 2);
  us* T1a0T = (us*)alloc((size_t)32 * 1504 * 2);
  us* T1b0T = (us*)alloc((size_t)32 * 1504 * 2);
  us* x1nT  = (us*)alloc((size_t)32 * 6016 * 2);
  us* x1pT  = (us*)alloc((size_t)32 * 6016 * 2);
  us* T1laT = (us*)alloc((size_t)32 * 6016 * 2);
  us* T1lbT = (us*)alloc((size_t)32 * 6016 * 2);
  us* T1uaT = (us*)alloc((size_t)32 * 6016 * 2);
  us* T1ubT = (us*)alloc((size_t)32 * 6016 * 2);
  us* x2nT  = (us*)alloc((size_t)32 * 4000 * 2);
  us* T1a2T = (us*)alloc((size_t)32 * 4000 * 2);
  us* T1b2T = (us*)alloc((size_t)32 * 4000 * 2);

  size_t used = (size_t)(p - (char*)d_ws);
  const size_t sizeT = ((size_t)6000 * 1504 + (size_t)4000 * 6016) * 2 + 1024;
  bool haveT = used + sizeT <= ws_size;
  us *B1t = nullptr, *B2t = nullptr;
  float *z0 = nullptr, *sx1 = nullptr;
  if (haveT) {
    B1t = (us*)alloc((size_t)6000 * 1504 * 2);
    B2t = (us*)alloc((size_t)4000 * 6016 * 2);
  } else {
    z0  = (float*)alloc((size_t)1500 * 32 * 4);
    sx1 = (float*)alloc((size_t)6000 * 32 * 4);
  }

  auto nb = [](long t) { return (unsigned)((t + 255) / 256); };
  auto P1 = [](const void* a) { PList q{}; q.p[0] = a; return q; };

  // 1. prep
  prep<<<381, 256, 0, stream>>>(x0, x1, x2, D1, D3, D5, W0, W1, W2,
                                x0T, x0dT, x1T, x1dT, x2dT, x2T, W0T, W1T, W2T,
                                ROWS, ZROWS * 32, x1nT);

  // 2. x0p = d1i * (B1 @ x1)   [atomic, k-split 4]
  gemm16<32, 0, false><<<dim3(94, 4), 256, 0, stream>>>(
      P1(B1), 6000, 1500, 6000, x1T, x1T, 6016,
      1.f, nullptr, nullptr, 0.f, D1, 1501, 2,
      r_x0p, nullptr, nullptr, nullptr, 0);

  if (haveT) {
    // 3. B1 -> B1t  (B1 L3-hot from step 2)
    convT<<<dim3(94, 24), 256, 0, stream>>>(B1, 6000, 1500, 6000, B1t, 1504);
  }

  // 4. x0p -> x0pT
  transpose32_k<<<dim3(24, 1), 256, 0, stream>>>(r_x0p, x0pT, nullptr, nullptr, 1500, 1504);

  // 5. x1n = d2 * (B1^T @ (d1i*x0))
  if (haveT) {
    gemm16<32, 1, false><<<dim3(375, 1), 256, 0, stream>>>(
        P1(B1t), 1504, 6000, 1504, x0dT, x0dT, 1504,
        1.f, nullptr, nullptr, 0.f, D2, 6001, 1,
        r_x1n, nullptr, x1nT, nullptr, 6016);
  } else {
    colcopy<<<nb(1500L * 32), 256, 0, stream>>>(z0, x0, 1500, D1, 1501, 2);
    mm_at<<<dim3(24, 24), 256, 0, stream>>>(B1, 6000, 1500, z0, r_x1n, 32, 6000, 63);
    scale_ip<<<nb(6000L * 32), 256, 0, stream>>>(r_x1n, 6000, D2, 6001, 1);
    transpose32_k<<<dim3(94, 1), 256, 0, stream>>>(r_x1n, x1nT, nullptr, nullptr, 6000, 6016);
  }

  // 6. x1p = B2 @ (d3*x2)   [atomic, k-split 2]
  gemm16<32, 0, false><<<dim3(375, 2), 256, 0, stream>>>(
      P1(B2), 4000, 6000, 4000, x2dT, x2dT, 4000,
      1.f, nullptr, nullptr, 0.f, nullptr, 0, 0,
      r_x1p, nullptr, nullptr, nullptr, 0);

  if (haveT) {
    // 7. B2 -> B2t (L3-hot)
    convT<<<dim3(63, 94), 256, 0, stream>>>(B2, 4000, 6000, 4000, B2t, 6016);
  }

  // 8. x1p -> x1pT
  transpose32_k<<<dim3(94, 1), 256, 0, stream>>>(r_x1p, x1pT, nullptr, nullptr, 6000, 6016);

  // 9. x2n = B2^T @ (d5p*x1)
  if (haveT) {
    gemm16<32, 1, false><<<dim3(250, 1), 256, 0, stream>>>(
        P1(B2t), 6016, 4000, 6016, x1dT, x1dT, 6016,
        1.f, nullptr, nullptr, 0.f, nullptr, 0, 0,
        r_x2n, nullptr, x2nT, nullptr, 4000);
  } else {
    colcopy<<<nb(6000L * 32), 256, 0, stream>>>(sx1, x1, 6000, D5, 6001, 2);
    mm_at<<<dim3(16, 32), 256, 0, stream>>>(B2, 4000, 6000, sx1, r_x2n, 32, 4000, 188);
    transpose32_k<<<dim3(63, 1), 256, 0, stream>>>(r_x2n, x2nT, nullptr, nullptr, 4000, 4000);
  }

  // ---- cheb L0 on (x0, x0p) ----
  gemm16<64, 0, false><<<dim3(94, 4), 256, 0, stream>>>(
      P1(L0), 1500, 1500, 1500, x0T, x0pT, 1504,
      1.f, nullptr, nullptr, 0.f, nullptr, 0, 0,
      r_T1a0, r_T1b0, nullptr, nullptr, 0);
  transpose32_k<<<dim3(24, 2), 256, 0, stream>>>(r_T1a0, T1a0T, r_T1b0, T1b0T, 1500, 1504);
  gemm16<64, 0, false><<<dim3(94, 4), 256, 0, stream>>>(
      P1(L0), 1500, 1500, 1500, T1a0T, T1b0T, 1504,
      2.f, x0, r_x0p, -1.f, nullptr, 0, 0,
      r_T2a0, r_T2b0, nullptr, nullptr, 0);

  // ---- cheb L1l on (x1n, x1) ----
  gemm16<64, 0, false><<<dim3(375, 2), 256, 0, stream>>>(
      P1(L1l), 6000, 6000, 6000, x1nT, x1T, 6016,
      1.f, nullptr, nullptr, 0.f, nullptr, 0, 0,
      r_T1la, r_T1lb, nullptr, nullptr, 0);
  transpose32_k<<<dim3(94, 2), 256, 0, stream>>>(r_T1la, T1laT, r_T1lb, T1lbT, 6000, 6016);
  gemm16<64, 0, false><<<dim3(375, 2), 256, 0, stream>>>(
      P1(L1l), 6000, 6000, 6000, T1laT, T1lbT, 6016,
      2.f, r_x1n, x1, -1.f, nullptr, 0, 0,
      r_T2la, r_T2lb, nullptr, nullptr, 0);

  // ---- cheb L1u on (x1, x1p) ----
  gemm16<64, 0, false><<<dim3(375, 2), 256, 0, stream>>>(
      P1(L1u), 6000, 6000, 6000, x1T, x1pT, 6016,
      1.f, nullptr, nullptr, 0.f, nullptr, 0, 0,
      r_T1ua, r_T1ub, nullptr, nullptr, 0);
  transpose32_k<<<dim3(94, 2), 256, 0, stream>>>(r_T1ua, T1uaT, r_T1ub, T1ubT, 6000, 6016);
  gemm16<64, 0, false><<<dim3(375, 2), 256, 0, stream>>>(
      P1(L1u), 6000, 6000, 6000, T1uaT, T1ubT, 6016,
      2.f, x1, r_x1p, -1.f, nullptr, 0, 0,
      r_T2ua, r_T2ub, nullptr, nullptr, 0);

  // ---- cheb L2 on (x2n, x2) ----
  gemm16<64, 0, false><<<dim3(250, 1), 256, 0, stream>>>(
      P1(L2), 4000, 4000, 4000, x2nT, x2T, 4000,
      1.f, nullptr, nullptr, 0.f, nullptr, 0, 0,
      r_T1a2, r_T1b2, T1a2T, T1b2T, 4000);
  gemm16<64, 0, false><<<dim3(250, 1), 256, 0, stream>>>(
      P1(L2), 4000, 4000, 4000, T1a2T, T1b2T, 4000,
      2.f, r_x2n, x2, -1.f, nullptr, 0, 0,
      r_T2a2, r_T2b2, nullptr, nullptr, 0);

  // ---- finals: y = relu(X @ W) ----
  {
    PList a{};
    a.p[0] = x0; a.p[1] = r_T1a0; a.p[2] = r_T2a0;
    a.p[3] = r_x0p; a.p[4] = r_T1b0; a.p[5] = r_T2b0;
    gemm16<32, 2, true><<<dim3(94, 1), 256, 0, stream>>>(
        a, 0, 1500, 192, W0T, W0T, 192,
        1.f, nullptr, nullptr, 0.f, nullptr, 0, 0,
        out, nullptr, nullptr, nullptr, 0);
  }
  {
    PList a{};
    a.p[0] = r_x1n; a.p[1] = r_T1la; a.p[2] = r_T2la;
    a.p[3] = x1;    a.p[4] = r_T1lb; a.p[5] = r_T2lb;
    a.p[6] = r_T1ua; a.p[7] = r_T2ua;
    a.p[8] = r_x1p; a.p[9] = r_T1ub; a.p[10] = r_T2ub;
    gemm16<32, 2, true><<<dim3(375, 1), 256, 0, stream>>>(
        a, 0, 6000, 352, W1T, W1T, 352,
        1.f, nullptr, nullptr, 0.f, nullptr, 0, 0,
        out + 48000, nullptr, nullptr, nullptr, 0);
  }
  {
    PList a{};
    a.p[0] = r_x2n; a.p[1] = r_T1a2; a.p[2] = r_T2a2;
    a.p[3] = x2;    a.p[4] = r_T1b2; a.p[5] = r_T2b2;
    gemm16<32, 2, true><<<dim3(250, 1), 256, 0, stream>>>(
        a, 0, 4000, 192, W2T, W2T, 192,
        1.f, nullptr, nullptr, 0.f, nullptr, 0, 0,
        out + 240000, nullptr, nullptr, nullptr, 0);
  }
}

// Round 5
// 439.175 us; speedup vs baseline: 1.0703x; 1.0703x over previous
//
#include <hip/hip_runtime.h>
#include <stdint.h>

typedef __attribute__((ext_vector_type(4))) float f32x4;
typedef __attribute__((ext_vector_type(8))) short s16x8;
typedef unsigned short us;

static __device__ __forceinline__ us f2bf(float f) {
  union { float f; uint32_t u; } v; v.f = f;
  uint32_t u = v.u;
  u += 0x7fffu + ((u >> 16) & 1u);   // round-to-nearest-even bf16
  return (us)(u >> 16);
}

// mode: 0 none, 1 multiply, 2 multiply-by-safe-reciprocal
static __device__ __forceinline__ float dval(const float* dv, long r, long dstr, int mode) {
  if (!dv || mode == 0) return 1.f;
  float d = dv[r * dstr];
  if (mode == 2) return (d != 0.f) ? 1.f / d : 0.f;
  return d;
}

// ---------------- transpose tile: src f32 [n][cols=32] (row stride lds_) -> dst bf16 [32][ldn] ----------------
// zero-pads dst cols [n, ldn) within covered tiles.
static __device__ void tpose_tile(const float* __restrict__ src, long lds_, int n,
                                  const float* __restrict__ dv, long dstr, int mode,
                                  us* __restrict__ dst, int ldn, int tile,
                                  us (*sm)[72]) {
  const int t = threadIdx.x;
  const int r0 = tile * 64;
  {
    const int rr = t & 63;
    const int cg = t >> 6;      // 0..3 -> cols cg*8..cg*8+7
    const int gr = r0 + rr;
    float sc = 1.f;
    f32x4 v0 = {0.f, 0.f, 0.f, 0.f}, v1 = {0.f, 0.f, 0.f, 0.f};
    if (gr < n) {
      sc = dval(dv, gr, dstr, mode);
      const float* sp = src + (long)gr * lds_ + cg * 8;
      v0 = *(const f32x4*)sp;
      v1 = *(const f32x4*)(sp + 4);
    }
#pragma unroll
    for (int j = 0; j < 4; ++j) {
      sm[cg * 8 + j][rr] = f2bf(v0[j] * sc);
      sm[cg * 8 + 4 + j][rr] = f2bf(v1[j] * sc);
    }
  }
  __syncthreads();
  {
    const int f = t >> 3;
    const int nc = (t & 7) * 8;
    if (r0 + nc < ldn) {
      s16x8 v = *(const s16x8*)&sm[f][nc];
      *(s16x8*)(dst + (size_t)f * ldn + r0 + nc) = v;
    }
  }
}

// up to two panels (blockIdx.y selects)
__global__ __launch_bounds__(256) void transpose32s(
    const float* __restrict__ sA, us* __restrict__ dA,
    const float* __restrict__ sB, us* __restrict__ dB,
    long lds_, int n, int ldn) {
  __shared__ us sm[32][72];
  const float* s = blockIdx.y ? sB : sA;
  us* d = blockIdx.y ? dB : dA;
  tpose_tile(s, lds_, n, nullptr, 0, 0, d, ldn, blockIdx.x, sm);
}

// ---------------- prep: input transposes + W packs + X-array zero/identity init ----------------
__global__ __launch_bounds__(256) void prep(
    const float* __restrict__ x0, const float* __restrict__ x1, const float* __restrict__ x2,
    const float* __restrict__ D1, const float* __restrict__ D3, const float* __restrict__ D5,
    const float* __restrict__ W0, const float* __restrict__ W1, const float* __restrict__ W2,
    us* x0T, us* x0dT, us* x1T, us* x1dT, us* x2T, us* x2dT,
    us* W0T, us* W1T, us* W2T,
    float* __restrict__ X0a, float* __restrict__ X1a, float* __restrict__ X2a) {
  __shared__ us sm[32][72];
  int b = blockIdx.x;
  if (b < 24)  { tpose_tile(x0, 32, 1500, nullptr, 0, 0, x0T, 1536, b, sm); return; }
  b -= 24;
  if (b < 24)  { tpose_tile(x0, 32, 1500, D1, 1501, 2, x0dT, 1536, b, sm); return; }
  b -= 24;
  if (b < 94)  { tpose_tile(x1, 32, 6000, nullptr, 0, 0, x1T, 6016, b, sm); return; }
  b -= 94;
  if (b < 94)  { tpose_tile(x1, 32, 6000, D5, 6001, 2, x1dT, 6016, b, sm); return; }
  b -= 94;
  if (b < 63)  { tpose_tile(x2, 32, 4000, nullptr, 0, 0, x2T, 4032, b, sm); return; }
  b -= 63;
  if (b < 63)  { tpose_tile(x2, 32, 4000, D3, 4001, 1, x2dT, 4032, b, sm); return; }
  b -= 63;
  if (b < 3) {
    const float* W = (b == 0) ? W0 : ((b == 1) ? W1 : W2);
    us* dst = (b == 0) ? W0T : ((b == 1) ? W1T : W2T);
    const int K = (b == 1) ? 11 : 6;
    const int C = K * 32;
    const int CP = (b == 1) ? 384 : 192;
    for (int idx = threadIdx.x; idx < 32 * CP; idx += 256) {
      int o = idx / CP, j = idx - o * CP;
      float v = 0.f;
      if (j < C) { int k = j >> 5, i = j & 31; v = W[((long)i * 32 + o) * K + k]; }
      dst[(size_t)o * CP + j] = f2bf(v);
    }
    return;
  }
  b -= 3;
  // X-array init: vectors of 4 floats; X0a 1500x192, X1a 6000x352, X2a 4000x192
  const long V0 = 1500L * 48, V1 = 6000L * 88, V2 = 4000L * 48;
  for (long i = (long)b * 256 + threadIdx.x; i < V0 + V1 + V2; i += 512L * 256) {
    f32x4 v = {0.f, 0.f, 0.f, 0.f};
    float* dst;
    if (i < V0) {
      long r = i / 48; int c0 = (int)(i - r * 48) * 4;
      if (c0 < 32) v = *(const f32x4*)(x0 + r * 32 + c0);
      dst = X0a + r * 192 + c0;
    } else if (i < V0 + V1) {
      long j = i - V0; long r = j / 88; int c0 = (int)(j - r * 88) * 4;
      if (c0 >= 96 && c0 < 128) v = *(const f32x4*)(x1 + r * 32 + (c0 - 96));
      dst = X1a + r * 352 + c0;
    } else {
      long j = i - V0 - V1; long r = j / 48; int c0 = (int)(j - r * 48) * 4;
      if (c0 >= 96 && c0 < 128) v = *(const f32x4*)(x2 + r * 32 + (c0 - 96));
      dst = X2a + r * 192 + c0;
    }
    *(f32x4*)dst = v;
  }
}

// ---------------- big transpose + f32->bf16: out(nO x ldo) = in^T (proven r1-r3) ----------------
__global__ __launch_bounds__(256) void convT(
    const float* __restrict__ in, int ldi, int nI, int nC,
    us* __restrict__ outT, int ldoT) {
  __shared__ us sT[64][72];
  const int t = threadIdx.x;
  const int tc0 = blockIdx.x * 64;
  const int tr0 = blockIdx.y * 64;
  const int c0 = (t & 15) * 4;
  const int r0 = (t >> 4) * 4;
  us ub[4][4];
#pragma unroll
  for (int j = 0; j < 4; ++j) {
    int gr = tr0 + r0 + j;
    f32x4 v = {0.f, 0.f, 0.f, 0.f};
    if (gr < nI) {
      const float* pI = in + (size_t)gr * ldi + tc0 + c0;
      if (tc0 + c0 + 3 < nC) {
        v = *(const f32x4*)pI;
      } else {
#pragma unroll
        for (int jj = 0; jj < 4; ++jj) if (tc0 + c0 + jj < nC) v[jj] = pI[jj];
      }
    }
#pragma unroll
    for (int jj = 0; jj < 4; ++jj) ub[j][jj] = f2bf(v[jj]);
  }
#pragma unroll
  for (int jj = 0; jj < 4; ++jj) {
    union { us u[4]; unsigned long long ll; } w;
#pragma unroll
    for (int j = 0; j < 4; ++j) w.u[j] = ub[j][jj];
    *(unsigned long long*)&sT[c0 + jj][r0] = w.ll;
  }
  __syncthreads();
#pragma unroll
  for (int p = 0; p < 2; ++p) {
    int orow = (t >> 3) + p * 32;
    int rcol = (t & 7) * 8;
    int grow = tc0 + orow;
    int gcol = tr0 + rcol;
    if (grow < nC && gcol < ldoT) {
      union { unsigned long long ll[2]; s16x8 v; } w;
      w.ll[0] = *(const unsigned long long*)&sT[orow][rcol];
      w.ll[1] = *(const unsigned long long*)&sT[orow][rcol + 4];
      *(s16x8*)(outT + (size_t)grow * ldoT + gcol) = w.v;
    }
  }
}

// ---------------- MFMA skinny GEMM, BK=64 (round-3 proven core + fused epilogue) ----------------
// C(n_rows x F) (+)= alpha * rowscale(A @ B) + beta*S ; B as two 32-row bf16 panels Bt0/Bt1
// (ldb must be >= ceil64(n_k); panels zero-padded). A f32 or bf16 row-major.
template <int F, bool ATOMIC, bool RELU, typename AT>
__global__ __launch_bounds__(256) void mm_mfma(
    const AT* __restrict__ A, long lda, int n_rows, int n_k,
    const us* __restrict__ Bt0, const us* __restrict__ Bt1, int ldb,
    float alpha, const float* __restrict__ S0, const float* __restrict__ S1, long ldS, float beta,
    const float* __restrict__ sv, long sstr, int smode,
    float* __restrict__ C0, float* __restrict__ C1, long ldc, int kchunk) {
  __shared__ __align__(16) us sA[64 * 64];
  __shared__ __align__(16) us sX[64 * 64];

  const int tid = threadIdx.x;
  const int k_begin = blockIdx.y * kchunk;
  const int k_end = min(n_k, k_begin + kchunk);
  if (k_begin >= k_end) return;
  const int nsteps = (k_end - k_begin + 63) >> 6;

  const int srow = tid >> 2;       // 0..63
  const int sslot = tid & 3;       // 16 elems each
  const int kc_off = sslot * 16;
  const long arowg = (long)blockIdx.x * 64 + srow;
  const bool arow_ok = arowg < n_rows;
  const bool xrow_ok = (F == 64) || (srow < 32);
  const us* xbase = ((srow < 32) ? Bt0 : Bt1) + (size_t)(srow & 31) * ldb;

  s16x8 abf0 = (s16x8)0, abf1 = (s16x8)0;
  f32x4 af0, af1, af2, af3;
  s16x8 x0r = (s16x8)0, x1r = (s16x8)0;

  auto load_tiles = [&](int k0) {
    int kc = k0 + kc_off;
    if constexpr (sizeof(AT) == 4) {
      af0 = f32x4{0, 0, 0, 0}; af1 = af0; af2 = af0; af3 = af0;
      if (arow_ok) {
        const float* ap = (const float*)A + (size_t)arowg * lda + kc;
        if (kc + 15 < n_k) {
          af0 = *(const f32x4*)ap; af1 = *(const f32x4*)(ap + 4);
          af2 = *(const f32x4*)(ap + 8); af3 = *(const f32x4*)(ap + 12);
        } else {
#pragma unroll
          for (int j = 0; j < 4; ++j) {
            if (kc + j < n_k) af0[j] = ap[j];
            if (kc + 4 + j < n_k) af1[j] = ap[4 + j];
            if (kc + 8 + j < n_k) af2[j] = ap[8 + j];
            if (kc + 12 + j < n_k) af3[j] = ap[12 + j];
          }
        }
      }
    } else {
      abf0 = (s16x8)0; abf1 = (s16x8)0;
      if (arow_ok) {
        const us* ap = (const us*)A + (size_t)arowg * lda + kc;
        if (kc + 15 < n_k) {
          abf0 = *(const s16x8*)ap; abf1 = *(const s16x8*)(ap + 8);
        } else {
#pragma unroll
          for (int j = 0; j < 8; ++j) {
            if (kc + j < n_k) abf0[j] = (short)ap[j];
            if (kc + 8 + j < n_k) abf1[j] = (short)ap[8 + j];
          }
        }
      }
    }
    if (xrow_ok) {
      x0r = *(const s16x8*)(xbase + kc);
      x1r = *(const s16x8*)(xbase + kc + 8);
    }
  };

  load_tiles(k_begin);

  const int wave = tid >> 6;
  const int lane = tid & 63;
  const int g = lane >> 4;
  const int r = lane & 15;
  const int wslot0 = ((2 * sslot) ^ (srow & 7)) * 8;
  const int wslot1 = ((2 * sslot + 1) ^ (srow & 7)) * 8;

  f32x4 acc[F / 16];
#pragma unroll
  for (int i = 0; i < F / 16; ++i) acc[i] = f32x4{0.f, 0.f, 0.f, 0.f};

  for (int s = 0; s < nsteps; ++s) {
    s16x8 pk0, pk1;
    if constexpr (sizeof(AT) == 4) {
#pragma unroll
      for (int j = 0; j < 4; ++j) {
        pk0[j] = (short)f2bf(af0[j]); pk0[4 + j] = (short)f2bf(af1[j]);
        pk1[j] = (short)f2bf(af2[j]); pk1[4 + j] = (short)f2bf(af3[j]);
      }
    } else { pk0 = abf0; pk1 = abf1; }
    *(s16x8*)&sA[srow * 64 + wslot0] = pk0;
    *(s16x8*)&sA[srow * 64 + wslot1] = pk1;
    if (xrow_ok) {
      *(s16x8*)&sX[srow * 64 + wslot0] = x0r;
      *(s16x8*)&sX[srow * 64 + wslot1] = x1r;
    }
    __syncthreads();
    if (s + 1 < nsteps) load_tiles(k_begin + (s + 1) * 64);

    const int arow = wave * 16 + r;
#pragma unroll
    for (int kk = 0; kk < 2; ++kk) {
      s16x8 afr = *(s16x8*)&sA[arow * 64 + (((kk * 4 + g) ^ (arow & 7)) << 3)];
#pragma unroll
      for (int nt = 0; nt < F / 16; ++nt) {
        int xc = nt * 16 + r;
        s16x8 bfr = *(s16x8*)&sX[xc * 64 + (((kk * 4 + g) ^ (xc & 7)) << 3)];
        acc[nt] = __builtin_amdgcn_mfma_f32_16x16x32_bf16(afr, bfr, acc[nt], 0, 0, 0);
      }
    }
    __syncthreads();
  }

  // fused epilogue: C/D layout col = lane&15, row = (lane>>4)*4 + reg
  float svv[4];
#pragma unroll
  for (int j = 0; j < 4; ++j) {
    long row = (long)blockIdx.x * 64 + wave * 16 + g * 4 + j;
    svv[j] = (row < n_rows) ? dval(sv, row, sstr, smode) : 0.f;
  }
#pragma unroll
  for (int nt = 0; nt < F / 16; ++nt) {
    float* C = (F == 64 && nt >= 2) ? C1 : C0;
    const float* S = (F == 64 && nt >= 2) ? S1 : S0;
    int col = ((F == 64) ? (nt & 1) : nt) * 16 + r;
#pragma unroll
    for (int j = 0; j < 4; ++j) {
      long row = (long)blockIdx.x * 64 + wave * 16 + g * 4 + j;
      if (row < n_rows) {
        float v = alpha * acc[nt][j] * svv[j];
        if (S0 && (!ATOMIC || blockIdx.y == 0)) v += beta * S[row * ldS + col];
        if (ATOMIC) {
          atomicAdd(&C[row * ldc + col], v);
        } else {
          if (RELU) v = fmaxf(v, 0.0f);
          C[row * ldc + col] = v;
        }
      }
    }
  }
}

// ---------------- fallback helpers (only if ws too small for B1t/B2t) ----------------
__global__ void colcopy(float* __restrict__ dst, const float* __restrict__ src, int n,
                        const float* __restrict__ dv, long dstr, int mode) {
  int idx = blockIdx.x * 256 + threadIdx.x;
  if (idx >= n * 32) return;
  dst[idx] = src[idx] * dval(dv, idx >> 5, dstr, mode);
}
__global__ void scale_ld(float* __restrict__ dst, long ld, int n,
                         const float* __restrict__ dv, long dstr, int mode) {
  int idx = blockIdx.x * 256 + threadIdx.x;
  if (idx >= n * 32) return;
  dst[(size_t)(idx >> 5) * ld + (idx & 31)] *= dval(dv, idx >> 5, dstr, mode);
}
__global__ __launch_bounds__(256) void mm_at(
    const float* __restrict__ A, int lda, int m,
    const float* __restrict__ X,
    float* __restrict__ C, int ldc, int n, int kchunk) {
  const int fg = threadIdx.x & 3;
  const int cg = threadIdx.x >> 2;
  const int c = blockIdx.x * 256 + cg * 4;
  const int k0 = blockIdx.y * kchunk;
  const int k1 = min(m, k0 + kchunk);
  const int f = fg * 8;
  float acc[4][8];
#pragma unroll
  for (int a = 0; a < 4; ++a)
#pragma unroll
    for (int b = 0; b < 8; ++b) acc[a][b] = 0.f;
  for (int k = k0; k < k1; ++k) {
    const float* Ar = A + (size_t)k * lda + c;
    f32x4 a;
    if (c + 3 < n) a = *(const f32x4*)Ar;
    else {
      a = f32x4{0.f, 0.f, 0.f, 0.f};
#pragma unroll
      for (int j = 0; j < 4; ++j) if (c + j < n) a[j] = Ar[j];
    }
    f32x4 xa = *(const f32x4*)(X + (size_t)k * 32 + f);
    f32x4 xb = *(const f32x4*)(X + (size_t)k * 32 + f + 4);
#pragma unroll
    for (int cc = 0; cc < 4; ++cc)
#pragma unroll
      for (int jj = 0; jj < 4; ++jj) {
        acc[cc][jj] += a[cc] * xa[jj];
        acc[cc][4 + jj] += a[cc] * xb[jj];
      }
  }
  if (c >= n) return;
#pragma unroll
  for (int cc = 0; cc < 4; ++cc) {
    if (c + cc >= n) break;
#pragma unroll
    for (int jj = 0; jj < 8; ++jj)
      atomicAdd(&C[(size_t)(c + cc) * ldc + f + jj], acc[cc][jj]);
  }
}

// ---------------- host ----------------

extern "C" void kernel_launch(void* const* d_in, const int* in_sizes, int n_in,
                              void* d_out, int out_size, void* d_ws, size_t ws_size,
                              hipStream_t stream) {
  (void)in_sizes; (void)n_in; (void)out_size;
  const float* x0  = (const float*)d_in[0];
  const float* x1  = (const float*)d_in[1];
  const float* x2  = (const float*)d_in[2];
  const float* B1  = (const float*)d_in[3];
  const float* B2  = (const float*)d_in[4];
  const float* L0  = (const float*)d_in[5];
  const float* L1l = (const float*)d_in[6];
  const float* L1u = (const float*)d_in[7];
  const float* L2  = (const float*)d_in[8];
  const float* D1  = (const float*)d_in[9];
  const float* D2  = (const float*)d_in[10];
  const float* D3  = (const float*)d_in[11];
  const float* D5  = (const float*)d_in[12];
  const float* W0  = (const float*)d_in[13];
  const float* W1  = (const float*)d_in[14];
  const float* W2  = (const float*)d_in[15];
  float* out = (float*)d_out;

  char* p = (char*)d_ws;
  auto alloc = [&](size_t b) { char* r = p; p += (b + 255) & ~(size_t)255; return r; };

  // input/interm transposed bf16 panels [32][ld]
  us* x0T   = (us*)alloc((size_t)32 * 1536 * 2);
  us* x0dT  = (us*)alloc((size_t)32 * 1536 * 2);
  us* x1T   = (us*)alloc((size_t)32 * 6016 * 2);
  us* x1dT  = (us*)alloc((size_t)32 * 6016 * 2);
  us* x2T   = (us*)alloc((size_t)32 * 4032 * 2);
  us* x2dT  = (us*)alloc((size_t)32 * 4032 * 2);
  us* x0pT  = (us*)alloc((size_t)32 * 1536 * 2);
  us* x1nT  = (us*)alloc((size_t)32 * 6016 * 2);
  us* x1pT  = (us*)alloc((size_t)32 * 6016 * 2);
  us* x2nT  = (us*)alloc((size_t)32 * 4032 * 2);
  us* T1aT  = (us*)alloc((size_t)32 * 6016 * 2);   // reused per cheb group
  us* T1bT  = (us*)alloc((size_t)32 * 6016 * 2);
  us* W0T   = (us*)alloc((size_t)32 * 192 * 2);
  us* W1T   = (us*)alloc((size_t)32 * 384 * 2);
  us* W2T   = (us*)alloc((size_t)32 * 192 * 2);

  // channel-stacked f32 arrays
  float* X0a = (float*)alloc((size_t)1500 * 192 * 4);
  float* X1a = (float*)alloc((size_t)6000 * 352 * 4);
  float* X2a = (float*)alloc((size_t)4000 * 192 * 4);

  // fallback scratch (tiny, always allocated)
  float* z0  = (float*)alloc((size_t)1500 * 32 * 4);
  float* sx1 = (float*)alloc((size_t)6000 * 32 * 4);

  // B1t/B2t share one region (sequential lifetimes)
  size_t used = (size_t)(p - (char*)d_ws);
  const size_t regionB = (size_t)4000 * 6016 * 2;    // 48.1 MB >= B1t's 18.4 MB
  bool haveT = used + regionB <= ws_size;
  us* B1t = nullptr; us* B2t = nullptr;
  if (haveT) { B1t = (us*)alloc(regionB); B2t = B1t; }

  auto nb = [](long t) { return (unsigned)((t + 255) / 256); };

  // 1. prep
  prep<<<877, 256, 0, stream>>>(x0, x1, x2, D1, D3, D5, W0, W1, W2,
                                x0T, x0dT, x1T, x1dT, x2T, x2dT, W0T, W1T, W2T,
                                X0a, X1a, X2a);

  // 2. x0p = d1i * (B1 @ x1) -> X0a ch3
  mm_mfma<32, true, false, float><<<dim3(24, 12), 256, 0, stream>>>(
      B1, 6000, 1500, 6000, x1T, x1T, 6016,
      1.f, nullptr, nullptr, 0, 0.f, D1, 1501, 2, X0a + 3 * 32, nullptr, 192, 512);
  transpose32s<<<dim3(24, 1), 256, 0, stream>>>(X0a + 3 * 32, x0pT, nullptr, nullptr, 192, 1500, 1536);

  // 3. x1n = d2 * (B1^T @ (d1i*x0)) -> X1a ch0
  if (haveT) {
    convT<<<dim3(94, 24), 256, 0, stream>>>(B1, 6000, 1500, 6000, B1t, 1536);
    mm_mfma<32, true, false, us><<<dim3(94, 3), 256, 0, stream>>>(
        B1t, 1536, 6000, 1536, x0dT, x0dT, 1536,
        1.f, nullptr, nullptr, 0, 0.f, D2, 6001, 1, X1a + 0 * 32, nullptr, 352, 512);
  } else {
    colcopy<<<nb(1500L * 32), 256, 0, stream>>>(z0, x0, 1500, D1, 1501, 2);
    mm_at<<<dim3(24, 24), 256, 0, stream>>>(B1, 6000, 1500, z0, X1a + 0 * 32, 352, 6000, 63);
    scale_ld<<<nb(6000L * 32), 256, 0, stream>>>(X1a + 0 * 32, 352, 6000, D2, 6001, 1);
  }
  transpose32s<<<dim3(94, 1), 256, 0, stream>>>(X1a + 0 * 32, x1nT, nullptr, nullptr, 352, 6000, 6016);

  // 4. x1p = B2 @ (d3*x2) -> X1a ch8
  mm_mfma<32, true, false, float><<<dim3(94, 4), 256, 0, stream>>>(
      B2, 4000, 6000, 4000, x2dT, x2dT, 4032,
      1.f, nullptr, nullptr, 0, 0.f, nullptr, 0, 0, X1a + 8 * 32, nullptr, 352, 1024);
  transpose32s<<<dim3(94, 1), 256, 0, stream>>>(X1a + 8 * 32, x1pT, nullptr, nullptr, 352, 6000, 6016);

  // 5. x2n = B2^T @ (d5p*x1) -> X2a ch0
  if (haveT) {
    convT<<<dim3(63, 94), 256, 0, stream>>>(B2, 4000, 6000, 4000, B2t, 6016);
    mm_mfma<32, true, false, us><<<dim3(63, 4), 256, 0, stream>>>(
        B2t, 6016, 4000, 6016, x1dT, x1dT, 6016,
        1.f, nullptr, nullptr, 0, 0.f, nullptr, 0, 0, X2a + 0 * 32, nullptr, 192, 1536);
  } else {
    colcopy<<<nb(6000L * 32), 256, 0, stream>>>(sx1, x1, 6000, D5, 6001, 2);
    mm_at<<<dim3(16, 32), 256, 0, stream>>>(B2, 4000, 6000, sx1, X2a + 0 * 32, 192, 4000, 188);
  }
  transpose32s<<<dim3(63, 1), 256, 0, stream>>>(X2a + 0 * 32, x2nT, nullptr, nullptr, 192, 4000, 4032);

  // ---- Chebyshev groups: p1: T1 = L@[a|b]; p2: T2 = 2*L@T1 - [a|b] ----
  // cheb L0 on (x0 ch0, x0p ch3) -> T1 ch1/ch4, T2 ch2/ch5
  mm_mfma<64, true, false, float><<<dim3(24, 8), 256, 0, stream>>>(
      L0, 1500, 1500, 1500, x0T, x0pT, 1536,
      1.f, nullptr, nullptr, 0, 0.f, nullptr, 0, 0, X0a + 1 * 32, X0a + 4 * 32, 192, 192);
  transpose32s<<<dim3(24, 2), 256, 0, stream>>>(X0a + 1 * 32, T1aT, X0a + 4 * 32, T1bT, 192, 1500, 1536);
  mm_mfma<64, true, false, float><<<dim3(24, 8), 256, 0, stream>>>(
      L0, 1500, 1500, 1500, T1aT, T1bT, 1536,
      2.f, X0a + 0 * 32, X0a + 3 * 32, 192, -1.f, nullptr, 0, 0, X0a + 2 * 32, X0a + 5 * 32, 192, 192);

  // cheb L1l on (x1n ch0, x1 ch3) -> T1 ch1/ch4, T2 ch2/ch5
  mm_mfma<64, true, false, float><<<dim3(94, 4), 256, 0, stream>>>(
      L1l, 6000, 6000, 6000, x1nT, x1T, 6016,
      1.f, nullptr, nullptr, 0, 0.f, nullptr, 0, 0, X1a + 1 * 32, X1a + 4 * 32, 352, 1536);
  transpose32s<<<dim3(94, 2), 256, 0, stream>>>(X1a + 1 * 32, T1aT, X1a + 4 * 32, T1bT, 352, 6000, 6016);
  mm_mfma<64, true, false, float><<<dim3(94, 4), 256, 0, stream>>>(
      L1l, 6000, 6000, 6000, T1aT, T1bT, 6016,
      2.f, X1a + 0 * 32, X1a + 3 * 32, 352, -1.f, nullptr, 0, 0, X1a + 2 * 32, X1a + 5 * 32, 352, 1536);

  // cheb L1u on (x1 ch3, x1p ch8) -> T1 ch6/ch9, T2 ch7/ch10
  mm_mfma<64, true, false, float><<<dim3(94, 4), 256, 0, stream>>>(
      L1u, 6000, 6000, 6000, x1T, x1pT, 6016,
      1.f, nullptr, nullptr, 0, 0.f, nullptr, 0, 0, X1a + 6 * 32, X1a + 9 * 32, 352, 1536);
  transpose32s<<<dim3(94, 2), 256, 0, stream>>>(X1a + 6 * 32, T1aT, X1a + 9 * 32, T1bT, 352, 6000, 6016);
  mm_mfma<64, true, false, float><<<dim3(94, 4), 256, 0, stream>>>(
      L1u, 6000, 6000, 6000, T1aT, T1bT, 6016,
      2.f, X1a + 3 * 32, X1a + 8 * 32, 352, -1.f, nullptr, 0, 0, X1a + 7 * 32, X1a + 10 * 32, 352, 1536);

  // cheb L2 on (x2n ch0, x2 ch3) -> T1 ch1/ch4, T2 ch2/ch5
  mm_mfma<64, true, false, float><<<dim3(63, 4), 256, 0, stream>>>(
      L2, 4000, 4000, 4000, x2nT, x2T, 4032,
      1.f, nullptr, nullptr, 0, 0.f, nullptr, 0, 0, X2a + 1 * 32, X2a + 4 * 32, 192, 1024);
  transpose32s<<<dim3(63, 2), 256, 0, stream>>>(X2a + 1 * 32, T1aT, X2a + 4 * 32, T1bT, 192, 4000, 4032);
  mm_mfma<64, true, false, float><<<dim3(63, 4), 256, 0, stream>>>(
      L2, 4000, 4000, 4000, T1aT, T1bT, 4032,
      2.f, X2a + 0 * 32, X2a + 3 * 32, 192, -1.f, nullptr, 0, 0, X2a + 2 * 32, X2a + 5 * 32, 192, 1024);

  // ---- finals: y = relu(X @ W), direct to d_out ----
  mm_mfma<32, false, true, float><<<dim3(24, 1), 256, 0, stream>>>(
      X0a, 192, 1500, 192, W0T, W0T, 192,
      1.f, nullptr, nullptr, 0, 0.f, nullptr, 0, 0, out, nullptr, 32, 192);
  mm_mfma<32, false, true, float><<<dim3(94, 1), 256, 0, stream>>>(
      X1a, 352, 6000, 352, W1T, W1T, 384,
      1.f, nullptr, nullptr, 0, 0.f, nullptr, 0, 0, out + 48000, nullptr, 32, 384);
  mm_mfma<32, false, true, float><<<dim3(63, 1), 256, 0, stream>>>(
      X2a, 192, 4000, 192, W2T, W2T, 192,
      1.f, nullptr, nullptr, 0, 0.f, nullptr, 0, 0, out + 240000, nullptr, 32, 192);
}

// Round 6
// 319.107 us; speedup vs baseline: 1.4730x; 1.3763x over previous
//
#include <hip/hip_runtime.h>
#include <stdint.h>

typedef __attribute__((ext_vector_type(4))) float f32x4;
typedef __attribute__((ext_vector_type(8))) short s16x8;
typedef unsigned short us;

static __device__ __forceinline__ us f2bf(float f) {
  union { float f; uint32_t u; } v; v.f = f;
  uint32_t u = v.u;
  u += 0x7fffu + ((u >> 16) & 1u);   // round-to-nearest-even bf16
  return (us)(u >> 16);
}

// mode: 0 none, 1 multiply, 2 multiply-by-safe-reciprocal
static __device__ __forceinline__ float dval(const float* dv, long r, long dstr, int mode) {
  if (!dv || mode == 0) return 1.f;
  float d = dv[r * dstr];
  if (mode == 2) return (d != 0.f) ? 1.f / d : 0.f;
  return d;
}

// ---------------- transpose tile: src f32 [n][32] (row stride lds_) -> dst bf16 [32][ldn] ----------------
static __device__ void tpose_tile(const float* __restrict__ src, long lds_, int n,
                                  const float* __restrict__ dv, long dstr, int mode,
                                  us* __restrict__ dst, int ldn, int tile,
                                  us (*sm)[72]) {
  const int t = threadIdx.x;
  const int r0 = tile * 64;
  {
    const int rr = t & 63;
    const int cg = t >> 6;
    const int gr = r0 + rr;
    float sc = 1.f;
    f32x4 v0 = {0.f, 0.f, 0.f, 0.f}, v1 = {0.f, 0.f, 0.f, 0.f};
    if (gr < n) {
      sc = dval(dv, gr, dstr, mode);
      const float* sp = src + (long)gr * lds_ + cg * 8;
      v0 = *(const f32x4*)sp;
      v1 = *(const f32x4*)(sp + 4);
    }
#pragma unroll
    for (int j = 0; j < 4; ++j) {
      sm[cg * 8 + j][rr] = f2bf(v0[j] * sc);
      sm[cg * 8 + 4 + j][rr] = f2bf(v1[j] * sc);
    }
  }
  __syncthreads();
  {
    const int f = t >> 3;
    const int nc = (t & 7) * 8;
    if (r0 + nc < ldn) {
      s16x8 v = *(const s16x8*)&sm[f][nc];
      *(s16x8*)(dst + (size_t)f * ldn + r0 + nc) = v;
    }
  }
}

// ---------------- batched small transpose ----------------
struct TSeg { const float* src; us* dst; long lds_; int n, ldn, start; };
struct TPack { TSeg t[8]; int nseg; };

__global__ __launch_bounds__(256) void tpose_batch(TPack P) {
  __shared__ us sm[32][72];
  int b = blockIdx.x;
  int si = P.nseg - 1;
  while (si > 0 && P.t[si].start > b) --si;
  const TSeg s = P.t[si];
  tpose_tile(s.src, s.lds_, s.n, nullptr, 0, 0, s.dst, s.ldn, b - s.start, sm);
}

// ---------------- prep: input transposes + W packs + X-array zero/identity init ----------------
__global__ __launch_bounds__(256) void prep(
    const float* __restrict__ x0, const float* __restrict__ x1, const float* __restrict__ x2,
    const float* __restrict__ D1, const float* __restrict__ D3, const float* __restrict__ D5,
    const float* __restrict__ W0, const float* __restrict__ W1, const float* __restrict__ W2,
    us* x0T, us* x0dT, us* x1T, us* x1dT, us* x2T, us* x2dT,
    us* W0T, us* W1T, us* W2T,
    float* __restrict__ X0a, float* __restrict__ X1a, float* __restrict__ X2a) {
  __shared__ us sm[32][72];
  int b = blockIdx.x;
  if (b < 24)  { tpose_tile(x0, 32, 1500, nullptr, 0, 0, x0T, 1536, b, sm); return; }
  b -= 24;
  if (b < 24)  { tpose_tile(x0, 32, 1500, D1, 1501, 2, x0dT, 1536, b, sm); return; }
  b -= 24;
  if (b < 94)  { tpose_tile(x1, 32, 6000, nullptr, 0, 0, x1T, 6016, b, sm); return; }
  b -= 94;
  if (b < 94)  { tpose_tile(x1, 32, 6000, D5, 6001, 2, x1dT, 6016, b, sm); return; }
  b -= 94;
  if (b < 63)  { tpose_tile(x2, 32, 4000, nullptr, 0, 0, x2T, 4032, b, sm); return; }
  b -= 63;
  if (b < 63)  { tpose_tile(x2, 32, 4000, D3, 4001, 1, x2dT, 4032, b, sm); return; }
  b -= 63;
  if (b < 3) {
    const float* W = (b == 0) ? W0 : ((b == 1) ? W1 : W2);
    us* dst = (b == 0) ? W0T : ((b == 1) ? W1T : W2T);
    const int K = (b == 1) ? 11 : 6;
    const int C = K * 32;
    const int CP = (b == 1) ? 384 : 192;
    for (int idx = threadIdx.x; idx < 32 * CP; idx += 256) {
      int o = idx / CP, j = idx - o * CP;
      float v = 0.f;
      if (j < C) { int k = j >> 5, i = j & 31; v = W[((long)i * 32 + o) * K + k]; }
      dst[(size_t)o * CP + j] = f2bf(v);
    }
    return;
  }
  b -= 3;
  const long V0 = 1500L * 48, V1 = 6000L * 88, V2 = 4000L * 48;
  for (long i = (long)b * 256 + threadIdx.x; i < V0 + V1 + V2; i += 512L * 256) {
    f32x4 v = {0.f, 0.f, 0.f, 0.f};
    float* dst;
    if (i < V0) {
      long r = i / 48; int c0 = (int)(i - r * 48) * 4;
      if (c0 < 32) v = *(const f32x4*)(x0 + r * 32 + c0);
      dst = X0a + r * 192 + c0;
    } else if (i < V0 + V1) {
      long j = i - V0; long r = j / 88; int c0 = (int)(j - r * 88) * 4;
      if (c0 >= 96 && c0 < 128) v = *(const f32x4*)(x1 + r * 32 + (c0 - 96));
      dst = X1a + r * 352 + c0;
    } else {
      long j = i - V0 - V1; long r = j / 48; int c0 = (int)(j - r * 48) * 4;
      if (c0 >= 96 && c0 < 128) v = *(const f32x4*)(x2 + r * 32 + (c0 - 96));
      dst = X2a + r * 192 + c0;
    }
    *(f32x4*)dst = v;
  }
}

// ---------------- batched big transpose f32 -> bf16^T ----------------
struct CSeg { const float* in; us* out; int ldi, nI, nC, ldoT, cx, start; };
struct CPack { CSeg c[2]; int nseg; };

static __device__ void convT_tile(const float* __restrict__ in, int ldi, int nI, int nC,
                                  us* __restrict__ outT, int ldoT, int bx, int by,
                                  us (*sT)[72]) {
  const int t = threadIdx.x;
  const int tc0 = bx * 64;
  const int tr0 = by * 64;
  const int c0 = (t & 15) * 4;
  const int r0 = (t >> 4) * 4;
  us ub[4][4];
#pragma unroll
  for (int j = 0; j < 4; ++j) {
    int gr = tr0 + r0 + j;
    f32x4 v = {0.f, 0.f, 0.f, 0.f};
    if (gr < nI) {
      const float* pI = in + (size_t)gr * ldi + tc0 + c0;
      if (tc0 + c0 + 3 < nC) {
        v = *(const f32x4*)pI;
      } else {
#pragma unroll
        for (int jj = 0; jj < 4; ++jj) if (tc0 + c0 + jj < nC) v[jj] = pI[jj];
      }
    }
#pragma unroll
    for (int jj = 0; jj < 4; ++jj) ub[j][jj] = f2bf(v[jj]);
  }
#pragma unroll
  for (int jj = 0; jj < 4; ++jj) {
    union { us u[4]; unsigned long long ll; } w;
#pragma unroll
    for (int j = 0; j < 4; ++j) w.u[j] = ub[j][jj];
    *(unsigned long long*)&sT[c0 + jj][r0] = w.ll;
  }
  __syncthreads();
#pragma unroll
  for (int p = 0; p < 2; ++p) {
    int orow = (t >> 3) + p * 32;
    int rcol = (t & 7) * 8;
    int grow = tc0 + orow;
    int gcol = tr0 + rcol;
    if (grow < nC && gcol < ldoT) {
      union { unsigned long long ll[2]; s16x8 v; } w;
      w.ll[0] = *(const unsigned long long*)&sT[orow][rcol];
      w.ll[1] = *(const unsigned long long*)&sT[orow][rcol + 4];
      *(s16x8*)(outT + (size_t)grow * ldoT + gcol) = w.v;
    }
  }
}

__global__ __launch_bounds__(256) void convT_batch(CPack P) {
  __shared__ us sT[64][72];
  int b = blockIdx.x;
  int si = P.nseg - 1;
  while (si > 0 && P.c[si].start > b) --si;
  const CSeg s = P.c[si];
  int local = b - s.start;
  convT_tile(s.in, s.ldi, s.nI, s.nC, s.out, s.ldoT, local % s.cx, local / s.cx, sT);
}

// ---------------- batched MFMA skinny GEMM (round-5 proven core) ----------------
struct Seg {
  const void* A; const us* Bt0; const us* Bt1;
  const float* S0; const float* S1; const float* sv;
  float* C0; float* C1;
  long lda, ldS, sstr, ldc;
  float alpha, beta;
  int n_rows, n_k, ldb, smode, kchunk, tiles, ky, start;
};
struct SegPack { Seg s[4]; int nseg; };

template <int F, bool RELU, typename AT>
__global__ __launch_bounds__(256) void mm_batch(SegPack P) {
  __shared__ __align__(16) us sA[64 * 64];
  __shared__ __align__(16) us sX[64 * 64];

  int b = blockIdx.x;
  int si = P.nseg - 1;
  while (si > 0 && P.s[si].start > b) --si;
  const Seg sg = P.s[si];
  const int local = b - sg.start;
  const int bx = local % sg.tiles;
  const int kidx = local / sg.tiles;

  const AT* __restrict__ A = (const AT*)sg.A;
  const int n_rows = sg.n_rows, n_k = sg.n_k, ldb = sg.ldb;
  const long lda = sg.lda;

  const int tid = threadIdx.x;
  const int k_begin = kidx * sg.kchunk;
  const int k_end = min(n_k, k_begin + sg.kchunk);
  const int nsteps = (k_end - k_begin + 63) >> 6;

  const int srow = tid >> 2;
  const int sslot = tid & 3;
  const int kc_off = sslot * 16;
  const long arowg = (long)bx * 64 + srow;
  const bool arow_ok = arowg < n_rows;
  const bool xrow_ok = (F == 64) || (srow < 32);
  const us* xbase = ((srow < 32) ? sg.Bt0 : sg.Bt1) + (size_t)(srow & 31) * ldb;

  s16x8 abf0 = (s16x8)0, abf1 = (s16x8)0;
  f32x4 af0, af1, af2, af3;
  s16x8 x0r = (s16x8)0, x1r = (s16x8)0;

  auto load_tiles = [&](int k0) {
    int kc = k0 + kc_off;
    if constexpr (sizeof(AT) == 4) {
      af0 = f32x4{0, 0, 0, 0}; af1 = af0; af2 = af0; af3 = af0;
      if (arow_ok) {
        const float* ap = (const float*)A + (size_t)arowg * lda + kc;
        if (kc + 15 < n_k) {
          af0 = *(const f32x4*)ap; af1 = *(const f32x4*)(ap + 4);
          af2 = *(const f32x4*)(ap + 8); af3 = *(const f32x4*)(ap + 12);
        } else {
#pragma unroll
          for (int j = 0; j < 4; ++j) {
            if (kc + j < n_k) af0[j] = ap[j];
            if (kc + 4 + j < n_k) af1[j] = ap[4 + j];
            if (kc + 8 + j < n_k) af2[j] = ap[8 + j];
            if (kc + 12 + j < n_k) af3[j] = ap[12 + j];
          }
        }
      }
    } else {
      abf0 = (s16x8)0; abf1 = (s16x8)0;
      if (arow_ok) {
        const us* ap = (const us*)A + (size_t)arowg * lda + kc;
        if (kc + 15 < n_k) {
          abf0 = *(const s16x8*)ap; abf1 = *(const s16x8*)(ap + 8);
        } else {
#pragma unroll
          for (int j = 0; j < 8; ++j) {
            if (kc + j < n_k) abf0[j] = (short)ap[j];
            if (kc + 8 + j < n_k) abf1[j] = (short)ap[8 + j];
          }
        }
      }
    }
    if (xrow_ok) {
      x0r = *(const s16x8*)(xbase + kc);
      x1r = *(const s16x8*)(xbase + kc + 8);
    }
  };

  load_tiles(k_begin);

  const int wave = tid >> 6;
  const int lane = tid & 63;
  const int g = lane >> 4;
  const int r = lane & 15;
  const int wslot0 = ((2 * sslot) ^ (srow & 7)) * 8;
  const int wslot1 = ((2 * sslot + 1) ^ (srow & 7)) * 8;

  f32x4 acc[F / 16];
#pragma unroll
  for (int i = 0; i < F / 16; ++i) acc[i] = f32x4{0.f, 0.f, 0.f, 0.f};

  for (int s = 0; s < nsteps; ++s) {
    s16x8 pk0, pk1;
    if constexpr (sizeof(AT) == 4) {
#pragma unroll
      for (int j = 0; j < 4; ++j) {
        pk0[j] = (short)f2bf(af0[j]); pk0[4 + j] = (short)f2bf(af1[j]);
        pk1[j] = (short)f2bf(af2[j]); pk1[4 + j] = (short)f2bf(af3[j]);
      }
    } else { pk0 = abf0; pk1 = abf1; }
    *(s16x8*)&sA[srow * 64 + wslot0] = pk0;
    *(s16x8*)&sA[srow * 64 + wslot1] = pk1;
    if (xrow_ok) {
      *(s16x8*)&sX[srow * 64 + wslot0] = x0r;
      *(s16x8*)&sX[srow * 64 + wslot1] = x1r;
    }
    __syncthreads();
    if (s + 1 < nsteps) load_tiles(k_begin + (s + 1) * 64);

    const int arow = wave * 16 + r;
#pragma unroll
    for (int kk = 0; kk < 2; ++kk) {
      s16x8 afr = *(s16x8*)&sA[arow * 64 + (((kk * 4 + g) ^ (arow & 7)) << 3)];
#pragma unroll
      for (int nt = 0; nt < F / 16; ++nt) {
        int xc = nt * 16 + r;
        s16x8 bfr = *(s16x8*)&sX[xc * 64 + (((kk * 4 + g) ^ (xc & 7)) << 3)];
        acc[nt] = __builtin_amdgcn_mfma_f32_16x16x32_bf16(afr, bfr, acc[nt], 0, 0, 0);
      }
    }
    __syncthreads();
  }

  float svv[4];
#pragma unroll
  for (int j = 0; j < 4; ++j) {
    long row = (long)bx * 64 + wave * 16 + g * 4 + j;
    svv[j] = (row < n_rows) ? dval(sg.sv, row, sg.sstr, sg.smode) : 0.f;
  }
#pragma unroll
  for (int nt = 0; nt < F / 16; ++nt) {
    float* C = (F == 64 && nt >= 2) ? sg.C1 : sg.C0;
    const float* S = (F == 64 && nt >= 2) ? sg.S1 : sg.S0;
    int col = ((F == 64) ? (nt & 1) : nt) * 16 + r;
#pragma unroll
    for (int j = 0; j < 4; ++j) {
      long row = (long)bx * 64 + wave * 16 + g * 4 + j;
      if (row < n_rows) {
        float v = sg.alpha * acc[nt][j] * svv[j];
        if (S && (sg.ky == 1 || kidx == 0)) v += sg.beta * S[row * sg.ldS + col];
        if (sg.ky > 1) {
          atomicAdd(&C[row * sg.ldc + col], v);
        } else {
          if (RELU) v = fmaxf(v, 0.0f);
          C[row * sg.ldc + col] = v;
        }
      }
    }
  }
}

// ---------------- fallback helpers (only if ws too small for B1t/B2t) ----------------
__global__ void colcopy(float* __restrict__ dst, const float* __restrict__ src, int n,
                        const float* __restrict__ dv, long dstr, int mode) {
  int idx = blockIdx.x * 256 + threadIdx.x;
  if (idx >= n * 32) return;
  dst[idx] = src[idx] * dval(dv, idx >> 5, dstr, mode);
}
__global__ void scale_ld(float* __restrict__ dst, long ld, int n,
                         const float* __restrict__ dv, long dstr, int mode) {
  int idx = blockIdx.x * 256 + threadIdx.x;
  if (idx >= n * 32) return;
  dst[(size_t)(idx >> 5) * ld + (idx & 31)] *= dval(dv, idx >> 5, dstr, mode);
}
__global__ __launch_bounds__(256) void mm_at(
    const float* __restrict__ A, int lda, int m,
    const float* __restrict__ X,
    float* __restrict__ C, int ldc, int n, int kchunk) {
  const int fg = threadIdx.x & 3;
  const int cg = threadIdx.x >> 2;
  const int c = blockIdx.x * 256 + cg * 4;
  const int k0 = blockIdx.y * kchunk;
  const int k1 = min(m, k0 + kchunk);
  const int f = fg * 8;
  float acc[4][8];
#pragma unroll
  for (int a = 0; a < 4; ++a)
#pragma unroll
    for (int b = 0; b < 8; ++b) acc[a][b] = 0.f;
  for (int k = k0; k < k1; ++k) {
    const float* Ar = A + (size_t)k * lda + c;
    f32x4 a;
    if (c + 3 < n) a = *(const f32x4*)Ar;
    else {
      a = f32x4{0.f, 0.f, 0.f, 0.f};
#pragma unroll
      for (int j = 0; j < 4; ++j) if (c + j < n) a[j] = Ar[j];
    }
    f32x4 xa = *(const f32x4*)(X + (size_t)k * 32 + f);
    f32x4 xb = *(const f32x4*)(X + (size_t)k * 32 + f + 4);
#pragma unroll
    for (int cc = 0; cc < 4; ++cc)
#pragma unroll
      for (int jj = 0; jj < 4; ++jj) {
        acc[cc][jj] += a[cc] * xa[jj];
        acc[cc][4 + jj] += a[cc] * xb[jj];
      }
  }
  if (c >= n) return;
#pragma unroll
  for (int cc = 0; cc < 4; ++cc) {
    if (c + cc >= n) break;
#pragma unroll
    for (int jj = 0; jj < 8; ++jj)
      atomicAdd(&C[(size_t)(c + cc) * ldc + f + jj], acc[cc][jj]);
  }
}

// ---------------- host ----------------

extern "C" void kernel_launch(void* const* d_in, const int* in_sizes, int n_in,
                              void* d_out, int out_size, void* d_ws, size_t ws_size,
                              hipStream_t stream) {
  (void)in_sizes; (void)n_in; (void)out_size;
  const float* x0  = (const float*)d_in[0];
  const float* x1  = (const float*)d_in[1];
  const float* x2  = (const float*)d_in[2];
  const float* B1  = (const float*)d_in[3];
  const float* B2  = (const float*)d_in[4];
  const float* L0  = (const float*)d_in[5];
  const float* L1l = (const float*)d_in[6];
  const float* L1u = (const float*)d_in[7];
  const float* L2  = (const float*)d_in[8];
  const float* D1  = (const float*)d_in[9];
  const float* D2  = (const float*)d_in[10];
  const float* D3  = (const float*)d_in[11];
  const float* D5  = (const float*)d_in[12];
  const float* W0  = (const float*)d_in[13];
  const float* W1  = (const float*)d_in[14];
  const float* W2  = (const float*)d_in[15];
  float* out = (float*)d_out;

  char* p = (char*)d_ws;
  auto alloc = [&](size_t b) { char* r = p; p += (b + 255) & ~(size_t)255; return r; };

  us* x0T   = (us*)alloc((size_t)32 * 1536 * 2);
  us* x0dT  = (us*)alloc((size_t)32 * 1536 * 2);
  us* x1T   = (us*)alloc((size_t)32 * 6016 * 2);
  us* x1dT  = (us*)alloc((size_t)32 * 6016 * 2);
  us* x2T   = (us*)alloc((size_t)32 * 4032 * 2);
  us* x2dT  = (us*)alloc((size_t)32 * 4032 * 2);
  us* x0pT  = (us*)alloc((size_t)32 * 1536 * 2);
  us* x1nT  = (us*)alloc((size_t)32 * 6016 * 2);
  us* x1pT  = (us*)alloc((size_t)32 * 6016 * 2);
  us* x2nT  = (us*)alloc((size_t)32 * 4032 * 2);
  us* T1a0T = (us*)alloc((size_t)32 * 1536 * 2);
  us* T1b0T = (us*)alloc((size_t)32 * 1536 * 2);
  us* T1laT = (us*)alloc((size_t)32 * 6016 * 2);
  us* T1lbT = (us*)alloc((size_t)32 * 6016 * 2);
  us* T1uaT = (us*)alloc((size_t)32 * 6016 * 2);
  us* T1ubT = (us*)alloc((size_t)32 * 6016 * 2);
  us* T1a2T = (us*)alloc((size_t)32 * 4032 * 2);
  us* T1b2T = (us*)alloc((size_t)32 * 4032 * 2);
  us* W0T   = (us*)alloc((size_t)32 * 192 * 2);
  us* W1T   = (us*)alloc((size_t)32 * 384 * 2);
  us* W2T   = (us*)alloc((size_t)32 * 192 * 2);

  float* X0a = (float*)alloc((size_t)1500 * 192 * 4);
  float* X1a = (float*)alloc((size_t)6000 * 352 * 4);
  float* X2a = (float*)alloc((size_t)4000 * 192 * 4);

  float* z0  = (float*)alloc((size_t)1500 * 32 * 4);
  float* sx1 = (float*)alloc((size_t)6000 * 32 * 4);

  size_t used = (size_t)(p - (char*)d_ws);
  bool haveT = used + (size_t)6000 * 1536 * 2 + (size_t)4000 * 6016 * 2 <= ws_size;
  us* B1t = nullptr; us* B2t = nullptr;
  if (haveT) {
    B1t = (us*)alloc((size_t)6000 * 1536 * 2);
    B2t = (us*)alloc((size_t)4000 * 6016 * 2);
  }

  auto nb = [](long t) { return (unsigned)((t + 255) / 256); };

  // helpers to build segments
  auto seg = [](const void* A, long lda, int n_rows, int n_k,
                const us* Bt0, const us* Bt1, int ldb,
                float alpha, const float* S0, const float* S1, long ldS, float beta,
                const float* sv, long sstr, int smode,
                float* C0, float* C1, long ldc,
                int kchunk, int tiles, int ky, int start) {
    Seg s;
    s.A = A; s.Bt0 = Bt0; s.Bt1 = Bt1; s.S0 = S0; s.S1 = S1; s.sv = sv;
    s.C0 = C0; s.C1 = C1; s.lda = lda; s.ldS = ldS; s.sstr = sstr; s.ldc = ldc;
    s.alpha = alpha; s.beta = beta; s.n_rows = n_rows; s.n_k = n_k; s.ldb = ldb;
    s.smode = smode; s.kchunk = kchunk; s.tiles = tiles; s.ky = ky; s.start = start;
    return s;
  };

  // 1. prep
  prep<<<877, 256, 0, stream>>>(x0, x1, x2, D1, D3, D5, W0, W1, W2,
                                x0T, x0dT, x1T, x1dT, x2T, x2dT, W0T, W1T, W2T,
                                X0a, X1a, X2a);

  // 2. B-GEMMs: x0p = d1i*(B1@x1) -> X0a ch3 ; x1p = B2@(d3*x2) -> X1a ch8
  {
    SegPack P{};
    P.nseg = 2;
    P.s[0] = seg(B1, 6000, 1500, 6000, x1T, x1T, 6016,
                 1.f, nullptr, nullptr, 0, 0.f, D1, 1501, 2,
                 X0a + 3 * 32, nullptr, 192, 768, 24, 8, 0);
    P.s[1] = seg(B2, 4000, 6000, 4000, x2dT, x2dT, 4032,
                 1.f, nullptr, nullptr, 0, 0.f, nullptr, 0, 0,
                 X1a + 8 * 32, nullptr, 352, 1344, 94, 3, 192);
    mm_batch<32, false, float><<<474, 256, 0, stream>>>(P);
  }

  // 3. convT batch: B1 -> B1t, B2 -> B2t (B1/B2 L3-hot from step 2)
  if (haveT) {
    CPack P{};
    P.nseg = 2;
    P.c[0] = CSeg{B1, B1t, 6000, 1500, 6000, 1536, 94, 0};
    P.c[1] = CSeg{B2, B2t, 4000, 6000, 4000, 6016, 63, 2256};
    convT_batch<<<8178, 256, 0, stream>>>(P);
  }

  // 4. Bt-GEMMs: x1n = d2*(B1t@x0d) -> X1a ch0 ; x2n = B2t@x1d -> X2a ch0
  if (haveT) {
    SegPack P{};
    P.nseg = 2;
    P.s[0] = seg(B1t, 1536, 6000, 1536, x0dT, x0dT, 1536,
                 1.f, nullptr, nullptr, 0, 0.f, D2, 6001, 1,
                 X1a + 0 * 32, nullptr, 352, 768, 94, 2, 0);
    P.s[1] = seg(B2t, 6016, 4000, 6016, x1dT, x1dT, 6016,
                 1.f, nullptr, nullptr, 0, 0.f, nullptr, 0, 0,
                 X2a + 0 * 32, nullptr, 192, 1536, 63, 4, 188);
    mm_batch<32, false, us><<<440, 256, 0, stream>>>(P);
  } else {
    colcopy<<<nb(1500L * 32), 256, 0, stream>>>(z0, x0, 1500, D1, 1501, 2);
    mm_at<<<dim3(24, 24), 256, 0, stream>>>(B1, 6000, 1500, z0, X1a + 0 * 32, 352, 6000, 63);
    scale_ld<<<nb(6000L * 32), 256, 0, stream>>>(X1a + 0 * 32, 352, 6000, D2, 6001, 1);
    colcopy<<<nb(6000L * 32), 256, 0, stream>>>(sx1, x1, 6000, D5, 6001, 2);
    mm_at<<<dim3(16, 32), 256, 0, stream>>>(B2, 4000, 6000, sx1, X2a + 0 * 32, 192, 4000, 188);
  }

  // 5. tpose batch: x0p, x1n, x1p, x2n
  {
    TPack P{};
    P.nseg = 4;
    P.t[0] = TSeg{X0a + 3 * 32, x0pT, 192, 1500, 1536, 0};
    P.t[1] = TSeg{X1a + 0 * 32, x1nT, 352, 6000, 6016, 24};
    P.t[2] = TSeg{X1a + 8 * 32, x1pT, 352, 6000, 6016, 118};
    P.t[3] = TSeg{X2a + 0 * 32, x2nT, 192, 4000, 4032, 212};
    tpose_batch<<<275, 256, 0, stream>>>(P);
  }

  // 6. cheb pass 1: T1 = L @ [a|b]  (all four L matrices, one dispatch)
  {
    SegPack P{};
    P.nseg = 4;
    P.s[0] = seg(L0, 1500, 1500, 1500, x0T, x0pT, 1536,
                 1.f, nullptr, nullptr, 0, 0.f, nullptr, 0, 0,
                 X0a + 1 * 32, X0a + 4 * 32, 192, 768, 24, 2, 0);
    P.s[1] = seg(L1l, 6000, 6000, 6000, x1nT, x1T, 6016,
                 1.f, nullptr, nullptr, 0, 0.f, nullptr, 0, 0,
                 X1a + 1 * 32, X1a + 4 * 32, 352, 3008, 94, 2, 48);
    P.s[2] = seg(L1u, 6000, 6000, 6000, x1T, x1pT, 6016,
                 1.f, nullptr, nullptr, 0, 0.f, nullptr, 0, 0,
                 X1a + 6 * 32, X1a + 9 * 32, 352, 3008, 94, 2, 236);
    P.s[3] = seg(L2, 4000, 4000, 4000, x2nT, x2T, 4032,
                 1.f, nullptr, nullptr, 0, 0.f, nullptr, 0, 0,
                 X2a + 1 * 32, X2a + 4 * 32, 192, 2048, 63, 2, 424);
    mm_batch<64, false, float><<<550, 256, 0, stream>>>(P);
  }

  // 7. tpose batch: all 8 T1 panels
  {
    TPack P{};
    P.nseg = 8;
    P.t[0] = TSeg{X0a + 1 * 32, T1a0T, 192, 1500, 1536, 0};
    P.t[1] = TSeg{X0a + 4 * 32, T1b0T, 192, 1500, 1536, 24};
    P.t[2] = TSeg{X1a + 1 * 32, T1laT, 352, 6000, 6016, 48};
    P.t[3] = TSeg{X1a + 4 * 32, T1lbT, 352, 6000, 6016, 142};
    P.t[4] = TSeg{X1a + 6 * 32, T1uaT, 352, 6000, 6016, 236};
    P.t[5] = TSeg{X1a + 9 * 32, T1ubT, 352, 6000, 6016, 330};
    P.t[6] = TSeg{X2a + 1 * 32, T1a2T, 192, 4000, 4032, 424};
    P.t[7] = TSeg{X2a + 4 * 32, T1b2T, 192, 4000, 4032, 487};
    tpose_batch<<<550, 256, 0, stream>>>(P);
  }

  // 8. cheb pass 2: T2 = 2*L@T1 - [a|b]
  {
    SegPack P{};
    P.nseg = 4;
    P.s[0] = seg(L0, 1500, 1500, 1500, T1a0T, T1b0T, 1536,
                 2.f, X0a + 0 * 32, X0a + 3 * 32, 192, -1.f, nullptr, 0, 0,
                 X0a + 2 * 32, X0a + 5 * 32, 192, 768, 24, 2, 0);
    P.s[1] = seg(L1l, 6000, 6000, 6000, T1laT, T1lbT, 6016,
                 2.f, X1a + 0 * 32, X1a + 3 * 32, 352, -1.f, nullptr, 0, 0,
                 X1a + 2 * 32, X1a + 5 * 32, 352, 3008, 94, 2, 48);
    P.s[2] = seg(L1u, 6000, 6000, 6000, T1uaT, T1ubT, 6016,
                 2.f, X1a + 3 * 32, X1a + 8 * 32, 352, -1.f, nullptr, 0, 0,
                 X1a + 7 * 32, X1a + 10 * 32, 352, 3008, 94, 2, 236);
    P.s[3] = seg(L2, 4000, 4000, 4000, T1a2T, T1b2T, 4032,
                 2.f, X2a + 0 * 32, X2a + 3 * 32, 192, -1.f, nullptr, 0, 0,
                 X2a + 2 * 32, X2a + 5 * 32, 192, 2048, 63, 2, 424);
    mm_batch<64, false, float><<<550, 256, 0, stream>>>(P);
  }

  // 9. finals: y = relu(X @ W) -> d_out
  {
    SegPack P{};
    P.nseg = 3;
    P.s[0] = seg(X0a, 192, 1500, 192, W0T, W0T, 192,
                 1.f, nullptr, nullptr, 0, 0.f, nullptr, 0, 0,
                 out, nullptr, 32, 192, 24, 1, 0);
    P.s[1] = seg(X1a, 352, 6000, 352, W1T, W1T, 384,
                 1.f, nullptr, nullptr, 0, 0.f, nullptr, 0, 0,
                 out + 48000, nullptr, 32, 384, 94, 1, 24);
    P.s[2] = seg(X2a, 192, 4000, 192, W2T, W2T, 192,
                 1.f, nullptr, nullptr, 0, 0.f, nullptr, 0, 0,
                 out + 240000, nullptr, 32, 192, 118, 1, 118);
    mm_batch<32, true, float><<<181, 256, 0, stream>>>(P);
  }
}

// Round 7
// 309.316 us; speedup vs baseline: 1.5196x; 1.0317x over previous
//
#include <hip/hip_runtime.h>
#include <stdint.h>

typedef __attribute__((ext_vector_type(4))) float f32x4;
typedef __attribute__((ext_vector_type(8))) short s16x8;
typedef unsigned short us;

static __device__ __forceinline__ us f2bf(float f) {
  union { float f; uint32_t u; } v; v.f = f;
  uint32_t u = v.u;
  u += 0x7fffu + ((u >> 16) & 1u);   // round-to-nearest-even bf16
  return (us)(u >> 16);
}

// mode: 0 none, 1 multiply, 2 multiply-by-safe-reciprocal
static __device__ __forceinline__ float dval(const float* dv, long r, long dstr, int mode) {
  if (!dv || mode == 0) return 1.f;
  float d = dv[r * dstr];
  if (mode == 2) return (d != 0.f) ? 1.f / d : 0.f;
  return d;
}

// ---------------- transpose tile: src f32 [n][32] (row stride lds_) -> dst bf16 [32][ldn] ----------------
static __device__ void tpose_tile(const float* __restrict__ src, long lds_, int n,
                                  const float* __restrict__ dv, long dstr, int mode,
                                  us* __restrict__ dst, int ldn, int tile,
                                  us (*sm)[72]) {
  const int t = threadIdx.x;
  const int r0 = tile * 64;
  {
    const int rr = t & 63;
    const int cg = t >> 6;
    const int gr = r0 + rr;
    float sc = 1.f;
    f32x4 v0 = {0.f, 0.f, 0.f, 0.f}, v1 = {0.f, 0.f, 0.f, 0.f};
    if (gr < n) {
      sc = dval(dv, gr, dstr, mode);
      const float* sp = src + (long)gr * lds_ + cg * 8;
      v0 = *(const f32x4*)sp;
      v1 = *(const f32x4*)(sp + 4);
    }
#pragma unroll
    for (int j = 0; j < 4; ++j) {
      sm[cg * 8 + j][rr] = f2bf(v0[j] * sc);
      sm[cg * 8 + 4 + j][rr] = f2bf(v1[j] * sc);
    }
  }
  __syncthreads();
  {
    const int f = t >> 3;
    const int nc = (t & 7) * 8;
    if (r0 + nc < ldn) {
      s16x8 v = *(const s16x8*)&sm[f][nc];
      *(s16x8*)(dst + (size_t)f * ldn + r0 + nc) = v;
    }
  }
}

static __device__ void convT_tile(const float* __restrict__ in, int ldi, int nI, int nC,
                                  us* __restrict__ outT, int ldoT, int bx, int by,
                                  us (*sT)[72]) {
  const int t = threadIdx.x;
  const int tc0 = bx * 64;
  const int tr0 = by * 64;
  const int c0 = (t & 15) * 4;
  const int r0 = (t >> 4) * 4;
  us ub[4][4];
#pragma unroll
  for (int j = 0; j < 4; ++j) {
    int gr = tr0 + r0 + j;
    f32x4 v = {0.f, 0.f, 0.f, 0.f};
    if (gr < nI) {
      const float* pI = in + (size_t)gr * ldi + tc0 + c0;
      if (tc0 + c0 + 3 < nC) {
        v = *(const f32x4*)pI;
      } else {
#pragma unroll
        for (int jj = 0; jj < 4; ++jj) if (tc0 + c0 + jj < nC) v[jj] = pI[jj];
      }
    }
#pragma unroll
    for (int jj = 0; jj < 4; ++jj) ub[j][jj] = f2bf(v[jj]);
  }
#pragma unroll
  for (int jj = 0; jj < 4; ++jj) {
    union { us u[4]; unsigned long long ll; } w;
#pragma unroll
    for (int j = 0; j < 4; ++j) w.u[j] = ub[j][jj];
    *(unsigned long long*)&sT[c0 + jj][r0] = w.ll;
  }
  __syncthreads();
#pragma unroll
  for (int p = 0; p < 2; ++p) {
    int orow = (t >> 3) + p * 32;
    int rcol = (t & 7) * 8;
    int grow = tc0 + orow;
    int gcol = tr0 + rcol;
    if (grow < nC && gcol < ldoT) {
      union { unsigned long long ll[2]; s16x8 v; } w;
      w.ll[0] = *(const unsigned long long*)&sT[orow][rcol];
      w.ll[1] = *(const unsigned long long*)&sT[orow][rcol + 4];
      *(s16x8*)(outT + (size_t)grow * ldoT + gcol) = w.v;
    }
  }
}

// ---------------- batched small transpose (standalone) ----------------
struct TSeg { const float* src; us* dst; int lds_, n, ldn, start; };
struct TPack { TSeg t[8]; int nseg; };

__global__ __launch_bounds__(256) void tpose_batch(TPack P) {
  __shared__ us sm[32][72];
  int b = blockIdx.x;
  int si = P.nseg - 1;
  while (si > 0 && P.t[si].start > b) --si;
  const TSeg s = P.t[si];
  tpose_tile(s.src, s.lds_, s.n, nullptr, 0, 0, s.dst, s.ldn, b - s.start, sm);
}

// ---------------- prep ----------------
__global__ __launch_bounds__(256) void prep(
    const float* __restrict__ x0, const float* __restrict__ x1, const float* __restrict__ x2,
    const float* __restrict__ D1, const float* __restrict__ D3, const float* __restrict__ D5,
    const float* __restrict__ W0, const float* __restrict__ W1, const float* __restrict__ W2,
    us* x0T, us* x0dT, us* x1T, us* x1dT, us* x2T, us* x2dT,
    us* W0T, us* W1T, us* W2T,
    float* __restrict__ X0a, float* __restrict__ X1a, float* __restrict__ X2a) {
  __shared__ us sm[32][72];
  int b = blockIdx.x;
  if (b < 24)  { tpose_tile(x0, 32, 1500, nullptr, 0, 0, x0T, 1536, b, sm); return; }
  b -= 24;
  if (b < 24)  { tpose_tile(x0, 32, 1500, D1, 1501, 2, x0dT, 1536, b, sm); return; }
  b -= 24;
  if (b < 94)  { tpose_tile(x1, 32, 6000, nullptr, 0, 0, x1T, 6016, b, sm); return; }
  b -= 94;
  if (b < 94)  { tpose_tile(x1, 32, 6000, D5, 6001, 2, x1dT, 6016, b, sm); return; }
  b -= 94;
  if (b < 63)  { tpose_tile(x2, 32, 4000, nullptr, 0, 0, x2T, 4032, b, sm); return; }
  b -= 63;
  if (b < 63)  { tpose_tile(x2, 32, 4000, D3, 4001, 1, x2dT, 4032, b, sm); return; }
  b -= 63;
  if (b < 3) {
    const float* W = (b == 0) ? W0 : ((b == 1) ? W1 : W2);
    us* dst = (b == 0) ? W0T : ((b == 1) ? W1T : W2T);
    const int K = (b == 1) ? 11 : 6;
    const int C = K * 32;
    const int CP = (b == 1) ? 384 : 192;
    for (int idx = threadIdx.x; idx < 32 * CP; idx += 256) {
      int o = idx / CP, j = idx - o * CP;
      float v = 0.f;
      if (j < C) { int k = j >> 5, i = j & 31; v = W[((long)i * 32 + o) * K + k]; }
      dst[(size_t)o * CP + j] = f2bf(v);
    }
    return;
  }
  b -= 3;
  const long V0 = 1500L * 48, V1 = 6000L * 88, V2 = 4000L * 48;
  for (long i = (long)b * 256 + threadIdx.x; i < V0 + V1 + V2; i += 512L * 256) {
    f32x4 v = {0.f, 0.f, 0.f, 0.f};
    float* dst;
    if (i < V0) {
      long r = i / 48; int c0 = (int)(i - r * 48) * 4;
      if (c0 < 32) v = *(const f32x4*)(x0 + r * 32 + c0);
      dst = X0a + r * 192 + c0;
    } else if (i < V0 + V1) {
      long j = i - V0; long r = j / 88; int c0 = (int)(j - r * 88) * 4;
      if (c0 >= 96 && c0 < 128) v = *(const f32x4*)(x1 + r * 32 + (c0 - 96));
      dst = X1a + r * 352 + c0;
    } else {
      long j = i - V0 - V1; long r = j / 48; int c0 = (int)(j - r * 48) * 4;
      if (c0 >= 96 && c0 < 128) v = *(const f32x4*)(x2 + r * 32 + (c0 - 96));
      dst = X2a + r * 192 + c0;
    }
    *(f32x4*)dst = v;
  }
}

// ---------------- mega: batched MFMA GEMM segs + convT segs + tpose segs ----------------
struct Seg {
  const void* A; us* Aout;
  const us* Bt0; const us* Bt1;
  const float* S0; const float* S1; const float* sv;
  float* C0; float* C1;
  float alpha, beta;
  int lda, ldao, ldS, sstr, ldc;
  int n_rows, n_k, ldb, smode, kchunk, tiles, ky, start;
};
struct CSeg { const float* in; us* out; int ldi, nI, nC, ldoT, cx, start; };
struct Mega {
  Seg s[4]; CSeg c[2]; TSeg t[2];
  int nseg, gemm_end, nconv, conv_end, ntp;
};

template <int F, bool RELU, typename AT>
__global__ __launch_bounds__(256) void mega(Mega P) {
  __shared__ __align__(16) us lds[64 * 128];
  const int b = blockIdx.x;
  if (b >= P.gemm_end) {
    if (b < P.conv_end) {
      int lb = b - P.gemm_end;
      int si = P.nconv - 1;
      while (si > 0 && P.c[si].start > lb) --si;
      const CSeg s = P.c[si];
      int l = lb - s.start;
      convT_tile(s.in, s.ldi, s.nI, s.nC, s.out, s.ldoT, l % s.cx, l / s.cx, (us(*)[72])lds);
    } else {
      int lb = b - P.conv_end;
      int si = P.ntp - 1;
      while (si > 0 && P.t[si].start > lb) --si;
      const TSeg s = P.t[si];
      tpose_tile(s.src, s.lds_, s.n, nullptr, 0, 0, s.dst, s.ldn, lb - s.start, (us(*)[72])lds);
    }
    return;
  }

  us* sA = lds;
  us* sX = lds + 64 * 64;

  int si = P.nseg - 1;
  while (si > 0 && P.s[si].start > b) --si;
  const Seg sg = P.s[si];
  const int local = b - sg.start;
  const int bx = local % sg.tiles;
  const int kidx = local / sg.tiles;

  const AT* __restrict__ A = (const AT*)sg.A;
  const int n_rows = sg.n_rows, n_k = sg.n_k, ldb = sg.ldb;

  const int tid = threadIdx.x;
  const int k_begin = kidx * sg.kchunk;
  const int k_end = min(n_k, k_begin + sg.kchunk);
  const int nsteps = (k_end - k_begin + 63) >> 6;

  const int srow = tid >> 2;
  const int sslot = tid & 3;
  const int kc_off = sslot * 16;
  const long arowg = (long)bx * 64 + srow;
  const bool arow_ok = arowg < n_rows;
  const bool xrow_ok = (F == 64) || (srow < 32);
  const us* xbase = ((srow < 32) ? sg.Bt0 : sg.Bt1) + (size_t)(srow & 31) * ldb;

  s16x8 abf0 = (s16x8)0, abf1 = (s16x8)0;
  f32x4 af0, af1, af2, af3;
  s16x8 x0r = (s16x8)0, x1r = (s16x8)0;

  auto load_tiles = [&](int k0) {
    int kc = k0 + kc_off;
    if constexpr (sizeof(AT) == 4) {
      af0 = f32x4{0, 0, 0, 0}; af1 = af0; af2 = af0; af3 = af0;
      if (arow_ok) {
        const float* ap = (const float*)A + (size_t)arowg * sg.lda + kc;
        if (kc + 15 < n_k) {
          af0 = *(const f32x4*)ap; af1 = *(const f32x4*)(ap + 4);
          af2 = *(const f32x4*)(ap + 8); af3 = *(const f32x4*)(ap + 12);
        } else {
#pragma unroll
          for (int j = 0; j < 4; ++j) {
            if (kc + j < n_k) af0[j] = ap[j];
            if (kc + 4 + j < n_k) af1[j] = ap[4 + j];
            if (kc + 8 + j < n_k) af2[j] = ap[8 + j];
            if (kc + 12 + j < n_k) af3[j] = ap[12 + j];
          }
        }
      }
    } else {
      abf0 = (s16x8)0; abf1 = (s16x8)0;
      if (arow_ok) {
        const us* ap = (const us*)A + (size_t)arowg * sg.lda + kc;
        if (kc + 15 < n_k) {
          abf0 = *(const s16x8*)ap; abf1 = *(const s16x8*)(ap + 8);
        } else {
#pragma unroll
          for (int j = 0; j < 8; ++j) {
            if (kc + j < n_k) abf0[j] = (short)ap[j];
            if (kc + 8 + j < n_k) abf1[j] = (short)ap[8 + j];
          }
        }
      }
    }
    if (xrow_ok) {
      x0r = *(const s16x8*)(xbase + kc);
      x1r = *(const s16x8*)(xbase + kc + 8);
    }
  };

  load_tiles(k_begin);

  const int wave = tid >> 6;
  const int lane = tid & 63;
  const int g = lane >> 4;
  const int r = lane & 15;
  const int wslot0 = ((2 * sslot) ^ (srow & 7)) * 8;
  const int wslot1 = ((2 * sslot + 1) ^ (srow & 7)) * 8;

  f32x4 acc[F / 16];
#pragma unroll
  for (int i = 0; i < F / 16; ++i) acc[i] = f32x4{0.f, 0.f, 0.f, 0.f};

  for (int s = 0; s < nsteps; ++s) {
    s16x8 pk0, pk1;
    if constexpr (sizeof(AT) == 4) {
#pragma unroll
      for (int j = 0; j < 4; ++j) {
        pk0[j] = (short)f2bf(af0[j]); pk0[4 + j] = (short)f2bf(af1[j]);
        pk1[j] = (short)f2bf(af2[j]); pk1[4 + j] = (short)f2bf(af3[j]);
      }
      // bf16-A side product (exact tile cover incl. zero pad)
      if (sg.Aout && arow_ok) {
        us* q = sg.Aout + (size_t)arowg * sg.ldao + (k_begin + s * 64 + kc_off);
        *(s16x8*)q = pk0;
        *(s16x8*)(q + 8) = pk1;
      }
    } else { pk0 = abf0; pk1 = abf1; }
    *(s16x8*)&sA[srow * 64 + wslot0] = pk0;
    *(s16x8*)&sA[srow * 64 + wslot1] = pk1;
    if (xrow_ok) {
      *(s16x8*)&sX[srow * 64 + wslot0] = x0r;
      *(s16x8*)&sX[srow * 64 + wslot1] = x1r;
    }
    __syncthreads();
    if (s + 1 < nsteps) load_tiles(k_begin + (s + 1) * 64);

    const int arow = wave * 16 + r;
#pragma unroll
    for (int kk = 0; kk < 2; ++kk) {
      s16x8 afr = *(s16x8*)&sA[arow * 64 + (((kk * 4 + g) ^ (arow & 7)) << 3)];
#pragma unroll
      for (int nt = 0; nt < F / 16; ++nt) {
        int xc = nt * 16 + r;
        s16x8 bfr = *(s16x8*)&sX[xc * 64 + (((kk * 4 + g) ^ (xc & 7)) << 3)];
        acc[nt] = __builtin_amdgcn_mfma_f32_16x16x32_bf16(afr, bfr, acc[nt], 0, 0, 0);
      }
    }
    __syncthreads();
  }

  float svv[4];
#pragma unroll
  for (int j = 0; j < 4; ++j) {
    long row = (long)bx * 64 + wave * 16 + g * 4 + j;
    svv[j] = (row < n_rows) ? dval(sg.sv, row, sg.sstr, sg.smode) : 0.f;
  }
#pragma unroll
  for (int nt = 0; nt < F / 16; ++nt) {
    float* C = (F == 64 && nt >= 2) ? sg.C1 : sg.C0;
    const float* S = (F == 64 && nt >= 2) ? sg.S1 : sg.S0;
    int col = ((F == 64) ? (nt & 1) : nt) * 16 + r;
#pragma unroll
    for (int j = 0; j < 4; ++j) {
      long row = (long)bx * 64 + wave * 16 + g * 4 + j;
      if (row < n_rows) {
        float v = sg.alpha * acc[nt][j] * svv[j];
        if (S && (sg.ky == 1 || kidx == 0)) v += sg.beta * S[row * (size_t)sg.ldS + col];
        if (sg.ky > 1) {
          atomicAdd(&C[row * (size_t)sg.ldc + col], v);
        } else {
          if (RELU) v = fmaxf(v, 0.0f);
          C[row * (size_t)sg.ldc + col] = v;
        }
      }
    }
  }
}

// ---------------- fallback helpers ----------------
__global__ void colcopy(float* __restrict__ dst, const float* __restrict__ src, int n,
                        const float* __restrict__ dv, long dstr, int mode) {
  int idx = blockIdx.x * 256 + threadIdx.x;
  if (idx >= n * 32) return;
  dst[idx] = src[idx] * dval(dv, idx >> 5, dstr, mode);
}
__global__ void scale_ld(float* __restrict__ dst, long ld, int n,
                         const float* __restrict__ dv, long dstr, int mode) {
  int idx = blockIdx.x * 256 + threadIdx.x;
  if (idx >= n * 32) return;
  dst[(size_t)(idx >> 5) * ld + (idx & 31)] *= dval(dv, idx >> 5, dstr, mode);
}
__global__ __launch_bounds__(256) void mm_at(
    const float* __restrict__ A, int lda, int m,
    const float* __restrict__ X,
    float* __restrict__ C, int ldc, int n, int kchunk) {
  const int fg = threadIdx.x & 3;
  const int cg = threadIdx.x >> 2;
  const int c = blockIdx.x * 256 + cg * 4;
  const int k0 = blockIdx.y * kchunk;
  const int k1 = min(m, k0 + kchunk);
  const int f = fg * 8;
  float acc[4][8];
#pragma unroll
  for (int a = 0; a < 4; ++a)
#pragma unroll
    for (int b = 0; b < 8; ++b) acc[a][b] = 0.f;
  for (int k = k0; k < k1; ++k) {
    const float* Ar = A + (size_t)k * lda + c;
    f32x4 a;
    if (c + 3 < n) a = *(const f32x4*)Ar;
    else {
      a = f32x4{0.f, 0.f, 0.f, 0.f};
#pragma unroll
      for (int j = 0; j < 4; ++j) if (c + j < n) a[j] = Ar[j];
    }
    f32x4 xa = *(const f32x4*)(X + (size_t)k * 32 + f);
    f32x4 xb = *(const f32x4*)(X + (size_t)k * 32 + f + 4);
#pragma unroll
    for (int cc = 0; cc < 4; ++cc)
#pragma unroll
      for (int jj = 0; jj < 4; ++jj) {
        acc[cc][jj] += a[cc] * xa[jj];
        acc[cc][4 + jj] += a[cc] * xb[jj];
      }
  }
  if (c >= n) return;
#pragma unroll
  for (int cc = 0; cc < 4; ++cc) {
    if (c + cc >= n) break;
#pragma unroll
    for (int jj = 0; jj < 8; ++jj)
      atomicAdd(&C[(size_t)(c + cc) * ldc + f + jj], acc[cc][jj]);
  }
}

// ---------------- host ----------------

extern "C" void kernel_launch(void* const* d_in, const int* in_sizes, int n_in,
                              void* d_out, int out_size, void* d_ws, size_t ws_size,
                              hipStream_t stream) {
  (void)in_sizes; (void)n_in; (void)out_size;
  const float* x0  = (const float*)d_in[0];
  const float* x1  = (const float*)d_in[1];
  const float* x2  = (const float*)d_in[2];
  const float* B1  = (const float*)d_in[3];
  const float* B2  = (const float*)d_in[4];
  const float* L0  = (const float*)d_in[5];
  const float* L1l = (const float*)d_in[6];
  const float* L1u = (const float*)d_in[7];
  const float* L2  = (const float*)d_in[8];
  const float* D1  = (const float*)d_in[9];
  const float* D2  = (const float*)d_in[10];
  const float* D3  = (const float*)d_in[11];
  const float* D5  = (const float*)d_in[12];
  const float* W0  = (const float*)d_in[13];
  const float* W1  = (const float*)d_in[14];
  const float* W2  = (const float*)d_in[15];
  float* out = (float*)d_out;

  char* p = (char*)d_ws;
  auto alloc = [&](size_t b) { char* r = p; p += (b + 255) & ~(size_t)255; return r; };

  us* x0T   = (us*)alloc((size_t)32 * 1536 * 2);
  us* x0dT  = (us*)alloc((size_t)32 * 1536 * 2);
  us* x1T   = (us*)alloc((size_t)32 * 6016 * 2);
  us* x1dT  = (us*)alloc((size_t)32 * 6016 * 2);
  us* x2T   = (us*)alloc((size_t)32 * 4032 * 2);
  us* x2dT  = (us*)alloc((size_t)32 * 4032 * 2);
  us* x0pT  = (us*)alloc((size_t)32 * 1536 * 2);
  us* x1nT  = (us*)alloc((size_t)32 * 6016 * 2);
  us* x1pT  = (us*)alloc((size_t)32 * 6016 * 2);
  us* x2nT  = (us*)alloc((size_t)32 * 4032 * 2);
  us* T1a0T = (us*)alloc((size_t)32 * 1536 * 2);
  us* T1b0T = (us*)alloc((size_t)32 * 1536 * 2);
  us* T1laT = (us*)alloc((size_t)32 * 6016 * 2);
  us* T1lbT = (us*)alloc((size_t)32 * 6016 * 2);
  us* T1uaT = (us*)alloc((size_t)32 * 6016 * 2);
  us* T1ubT = (us*)alloc((size_t)32 * 6016 * 2);
  us* T1a2T = (us*)alloc((size_t)32 * 4032 * 2);
  us* T1b2T = (us*)alloc((size_t)32 * 4032 * 2);
  us* W0T   = (us*)alloc((size_t)32 * 192 * 2);
  us* W1T   = (us*)alloc((size_t)32 * 384 * 2);
  us* W2T   = (us*)alloc((size_t)32 * 192 * 2);

  float* X0a = (float*)alloc((size_t)1500 * 192 * 4);
  float* X1a = (float*)alloc((size_t)6000 * 352 * 4);
  float* X2a = (float*)alloc((size_t)4000 * 192 * 4);

  float* z0  = (float*)alloc((size_t)1500 * 32 * 4);
  float* sx1 = (float*)alloc((size_t)6000 * 32 * 4);

  size_t used = (size_t)(p - (char*)d_ws);
  const size_t needB  = (size_t)6000 * 1536 * 2 + (size_t)4000 * 6016 * 2 + 1024;
  const size_t needL1 = 2 * (size_t)6000 * 6016 * 2 + 1024;
  const size_t needL02 = (size_t)1500 * 1536 * 2 + (size_t)4000 * 4032 * 2 + 1024;
  bool haveB = used + needB <= ws_size;
  int tier = 0;
  if (haveB) {
    if (used + needB + needL1 + needL02 <= ws_size) tier = 2;
    else if (used + needB + needL1 <= ws_size) tier = 1;
  }
  us *B1t = nullptr, *B2t = nullptr;
  us *L0bf = nullptr, *L1lbf = nullptr, *L1ubf = nullptr, *L2bf = nullptr;
  if (haveB) {
    B1t = (us*)alloc((size_t)6000 * 1536 * 2);
    B2t = (us*)alloc((size_t)4000 * 6016 * 2);
  }
  if (tier >= 1) {
    L1lbf = (us*)alloc((size_t)6000 * 6016 * 2);
    L1ubf = (us*)alloc((size_t)6000 * 6016 * 2);
  }
  if (tier >= 2) {
    L0bf = (us*)alloc((size_t)1500 * 1536 * 2);
    L2bf = (us*)alloc((size_t)4000 * 4032 * 2);
  }

  auto nb = [](long t) { return (unsigned)((t + 255) / 256); };
  auto seg = [](const void* A, us* Aout, int lda, int ldao, int n_rows, int n_k,
                const us* Bt0, const us* Bt1, int ldb,
                float alpha, const float* S0, const float* S1, int ldS, float beta,
                const float* sv, int sstr, int smode,
                float* C0, float* C1, int ldc,
                int kchunk, int tiles, int ky, int start) {
    Seg s;
    s.A = A; s.Aout = Aout; s.Bt0 = Bt0; s.Bt1 = Bt1; s.S0 = S0; s.S1 = S1; s.sv = sv;
    s.C0 = C0; s.C1 = C1; s.alpha = alpha; s.beta = beta;
    s.lda = lda; s.ldao = ldao; s.ldS = ldS; s.sstr = sstr; s.ldc = ldc;
    s.n_rows = n_rows; s.n_k = n_k; s.ldb = ldb; s.smode = smode;
    s.kchunk = kchunk; s.tiles = tiles; s.ky = ky; s.start = start;
    return s;
  };

  // 1. prep
  prep<<<877, 256, 0, stream>>>(x0, x1, x2, D1, D3, D5, W0, W1, W2,
                                x0T, x0dT, x1T, x1dT, x2T, x2dT, W0T, W1T, W2T,
                                X0a, X1a, X2a);

  // M1: B-GEMMs (x0p, x1p) + convT(B1->B1t, B2->B2t) in ONE dispatch
  {
    Mega P{};
    P.nseg = 2;
    P.s[0] = seg(B1, nullptr, 6000, 0, 1500, 6000, x1T, x1T, 6016,
                 1.f, nullptr, nullptr, 0, 0.f, D1, 1501, 2,
                 X0a + 3 * 32, nullptr, 192, 768, 24, 8, 0);
    P.s[1] = seg(B2, nullptr, 4000, 0, 6000, 4000, x2dT, x2dT, 4032,
                 1.f, nullptr, nullptr, 0, 0.f, nullptr, 0, 0,
                 X1a + 8 * 32, nullptr, 352, 1344, 94, 3, 192);
    P.gemm_end = 474;
    if (haveB) {
      P.nconv = 2;
      P.c[0] = CSeg{B1, B1t, 6000, 1500, 6000, 1536, 94, 0};
      P.c[1] = CSeg{B2, B2t, 4000, 6000, 4000, 6016, 63, 2256};
      P.conv_end = 474 + 8178;
    } else {
      P.nconv = 0; P.conv_end = 474;
    }
    P.ntp = 0;
    mega<32, false, float><<<P.conv_end, 256, 0, stream>>>(P);
  }

  // M2: Bt-GEMMs (x1n, x2n) + tpose(x0p, x1p)
  if (haveB) {
    Mega P{};
    P.nseg = 2;
    P.s[0] = seg(B1t, nullptr, 1536, 0, 6000, 1536, x0dT, x0dT, 1536,
                 1.f, nullptr, nullptr, 0, 0.f, D2, 6001, 1,
                 X1a + 0 * 32, nullptr, 352, 768, 94, 2, 0);
    P.s[1] = seg(B2t, nullptr, 6016, 0, 4000, 6016, x1dT, x1dT, 6016,
                 1.f, nullptr, nullptr, 0, 0.f, nullptr, 0, 0,
                 X2a + 0 * 32, nullptr, 192, 1536, 63, 4, 188);
    P.gemm_end = 440;
    P.nconv = 0; P.conv_end = 440;
    P.ntp = 2;
    P.t[0] = TSeg{X0a + 3 * 32, x0pT, 192, 1500, 1536, 0};
    P.t[1] = TSeg{X1a + 8 * 32, x1pT, 352, 6000, 6016, 24};
    mega<32, false, us><<<558, 256, 0, stream>>>(P);
  } else {
    colcopy<<<nb(1500L * 32), 256, 0, stream>>>(z0, x0, 1500, D1, 1501, 2);
    mm_at<<<dim3(24, 24), 256, 0, stream>>>(B1, 6000, 1500, z0, X1a + 0 * 32, 352, 6000, 63);
    scale_ld<<<nb(6000L * 32), 256, 0, stream>>>(X1a + 0 * 32, 352, 6000, D2, 6001, 1);
    colcopy<<<nb(6000L * 32), 256, 0, stream>>>(sx1, x1, 6000, D5, 6001, 2);
    mm_at<<<dim3(16, 32), 256, 0, stream>>>(B2, 4000, 6000, sx1, X2a + 0 * 32, 192, 4000, 188);
    TPack T{};
    T.nseg = 2;
    T.t[0] = TSeg{X0a + 3 * 32, x0pT, 192, 1500, 1536, 0};
    T.t[1] = TSeg{X1a + 8 * 32, x1pT, 352, 6000, 6016, 24};
    tpose_batch<<<118, 256, 0, stream>>>(T);
  }

  // M3: tpose x1n, x2n
  {
    TPack T{};
    T.nseg = 2;
    T.t[0] = TSeg{X1a + 0 * 32, x1nT, 352, 6000, 6016, 0};
    T.t[1] = TSeg{X2a + 0 * 32, x2nT, 192, 4000, 4032, 94};
    tpose_batch<<<157, 256, 0, stream>>>(T);
  }

  // M4: cheb pass 1 (T1 = L @ [a|b]) + bf16-L side product
  {
    Mega P{};
    P.nseg = 4;
    P.s[0] = seg(L0, L0bf, 1500, 1536, 1500, 1500, x0T, x0pT, 1536,
                 1.f, nullptr, nullptr, 0, 0.f, nullptr, 0, 0,
                 X0a + 1 * 32, X0a + 4 * 32, 192, 768, 24, 2, 0);
    P.s[1] = seg(L1l, L1lbf, 6000, 6016, 6000, 6000, x1nT, x1T, 6016,
                 1.f, nullptr, nullptr, 0, 0.f, nullptr, 0, 0,
                 X1a + 1 * 32, X1a + 4 * 32, 352, 3008, 94, 2, 48);
    P.s[2] = seg(L1u, L1ubf, 6000, 6016, 6000, 6000, x1T, x1pT, 6016,
                 1.f, nullptr, nullptr, 0, 0.f, nullptr, 0, 0,
                 X1a + 6 * 32, X1a + 9 * 32, 352, 3008, 94, 2, 236);
    P.s[3] = seg(L2, L2bf, 4000, 4032, 4000, 4000, x2nT, x2T, 4032,
                 1.f, nullptr, nullptr, 0, 0.f, nullptr, 0, 0,
                 X2a + 1 * 32, X2a + 4 * 32, 192, 2048, 63, 2, 424);
    P.gemm_end = 550; P.nconv = 0; P.conv_end = 550; P.ntp = 0;
    mega<64, false, float><<<550, 256, 0, stream>>>(P);
  }

  // M5: tpose all 8 T1 panels
  {
    TPack T{};
    T.nseg = 8;
    T.t[0] = TSeg{X0a + 1 * 32, T1a0T, 192, 1500, 1536, 0};
    T.t[1] = TSeg{X0a + 4 * 32, T1b0T, 192, 1500, 1536, 24};
    T.t[2] = TSeg{X1a + 1 * 32, T1laT, 352, 6000, 6016, 48};
    T.t[3] = TSeg{X1a + 4 * 32, T1lbT, 352, 6000, 6016, 142};
    T.t[4] = TSeg{X1a + 6 * 32, T1uaT, 352, 6000, 6016, 236};
    T.t[5] = TSeg{X1a + 9 * 32, T1ubT, 352, 6000, 6016, 330};
    T.t[6] = TSeg{X2a + 1 * 32, T1a2T, 192, 4000, 4032, 424};
    T.t[7] = TSeg{X2a + 4 * 32, T1b2T, 192, 4000, 4032, 487};
    tpose_batch<<<550, 256, 0, stream>>>(T);
  }

  // M6: cheb pass 2 (T2 = 2*L@T1 - [a|b]), bf16-L where available
  {
    if (tier == 2) {
      Mega P{};
      P.nseg = 4;
      P.s[0] = seg(L0bf, nullptr, 1536, 0, 1500, 1536, T1a0T, T1b0T, 1536,
                   2.f, X0a + 0 * 32, X0a + 3 * 32, 192, -1.f, nullptr, 0, 0,
                   X0a + 2 * 32, X0a + 5 * 32, 192, 768, 24, 2, 0);
      P.s[1] = seg(L1lbf, nullptr, 6016, 0, 6000, 6016, T1laT, T1lbT, 6016,
                   2.f, X1a + 0 * 32, X1a + 3 * 32, 352, -1.f, nullptr, 0, 0,
                   X1a + 2 * 32, X1a + 5 * 32, 352, 3008, 94, 2, 48);
      P.s[2] = seg(L1ubf, nullptr, 6016, 0, 6000, 6016, T1uaT, T1ubT, 6016,
                   2.f, X1a + 3 * 32, X1a + 8 * 32, 352, -1.f, nullptr, 0, 0,
                   X1a + 7 * 32, X1a + 10 * 32, 352, 3008, 94, 2, 236);
      P.s[3] = seg(L2bf, nullptr, 4032, 0, 4000, 4032, T1a2T, T1b2T, 4032,
                   2.f, X2a + 0 * 32, X2a + 3 * 32, 192, -1.f, nullptr, 0, 0,
                   X2a + 2 * 32, X2a + 5 * 32, 192, 2048, 63, 2, 424);
      P.gemm_end = 550; P.nconv = 0; P.conv_end = 550; P.ntp = 0;
      mega<64, false, us><<<550, 256, 0, stream>>>(P);
    } else if (tier == 1) {
      Mega P{};
      P.nseg = 2;
      P.s[0] = seg(L1lbf, nullptr, 6016, 0, 6000, 6016, T1laT, T1lbT, 6016,
                   2.f, X1a + 0 * 32, X1a + 3 * 32, 352, -1.f, nullptr, 0, 0,
                   X1a + 2 * 32, X1a + 5 * 32, 352, 3008, 94, 2, 0);
      P.s[1] = seg(L1ubf, nullptr, 6016, 0, 6000, 6016, T1uaT, T1ubT, 6016,
                   2.f, X1a + 3 * 32, X1a + 8 * 32, 352, -1.f, nullptr, 0, 0,
                   X1a + 7 * 32, X1a + 10 * 32, 352, 3008, 94, 2, 188);
      P.gemm_end = 376; P.nconv = 0; P.conv_end = 376; P.ntp = 0;
      mega<64, false, us><<<376, 256, 0, stream>>>(P);
      Mega Q{};
      Q.nseg = 2;
      Q.s[0] = seg(L0, nullptr, 1500, 0, 1500, 1500, T1a0T, T1b0T, 1536,
                   2.f, X0a + 0 * 32, X0a + 3 * 32, 192, -1.f, nullptr, 0, 0,
                   X0a + 2 * 32, X0a + 5 * 32, 192, 768, 24, 2, 0);
      Q.s[1] = seg(L2, nullptr, 4000, 0, 4000, 4000, T1a2T, T1b2T, 4032,
                   2.f, X2a + 0 * 32, X2a + 3 * 32, 192, -1.f, nullptr, 0, 0,
                   X2a + 2 * 32, X2a + 5 * 32, 192, 2048, 63, 2, 48);
      Q.gemm_end = 174; Q.nconv = 0; Q.conv_end = 174; Q.ntp = 0;
      mega<64, false, float><<<174, 256, 0, stream>>>(Q);
    } else {
      Mega P{};
      P.nseg = 4;
      P.s[0] = seg(L0, nullptr, 1500, 0, 1500, 1500, T1a0T, T1b0T, 1536,
                   2.f, X0a + 0 * 32, X0a + 3 * 32, 192, -1.f, nullptr, 0, 0,
                   X0a + 2 * 32, X0a + 5 * 32, 192, 768, 24, 2, 0);
      P.s[1] = seg(L1l, nullptr, 6000, 0, 6000, 6000, T1laT, T1lbT, 6016,
                   2.f, X1a + 0 * 32, X1a + 3 * 32, 352, -1.f, nullptr, 0, 0,
                   X1a + 2 * 32, X1a + 5 * 32, 352, 3008, 94, 2, 48);
      P.s[2] = seg(L1u, nullptr, 6000, 0, 6000, 6000, T1uaT, T1ubT, 6016,
                   2.f, X1a + 3 * 32, X1a + 8 * 32, 352, -1.f, nullptr, 0, 0,
                   X1a + 7 * 32, X1a + 10 * 32, 352, 3008, 94, 2, 236);
      P.s[3] = seg(L2, nullptr, 4000, 0, 4000, 4000, T1a2T, T1b2T, 4032,
                   2.f, X2a + 0 * 32, X2a + 3 * 32, 192, -1.f, nullptr, 0, 0,
                   X2a + 2 * 32, X2a + 5 * 32, 192, 2048, 63, 2, 424);
      P.gemm_end = 550; P.nconv = 0; P.conv_end = 550; P.ntp = 0;
      mega<64, false, float><<<550, 256, 0, stream>>>(P);
    }
  }

  // M7: finals y = relu(X @ W)
  {
    Mega P{};
    P.nseg = 3;
    P.s[0] = seg(X0a, nullptr, 192, 0, 1500, 192, W0T, W0T, 192,
                 1.f, nullptr, nullptr, 0, 0.f, nullptr, 0, 0,
                 out, nullptr, 32, 192, 24, 1, 0);
    P.s[1] = seg(X1a, nullptr, 352, 0, 6000, 352, W1T, W1T, 384,
                 1.f, nullptr, nullptr, 0, 0.f, nullptr, 0, 0,
                 out + 48000, nullptr, 32, 384, 94, 1, 24);
    P.s[2] = seg(X2a, nullptr, 192, 0, 4000, 192, W2T, W2T, 192,
                 1.f, nullptr, nullptr, 0, 0.f, nullptr, 0, 0,
                 out + 240000, nullptr, 32, 192, 63, 1, 118);
    P.gemm_end = 181; P.nconv = 0; P.conv_end = 181; P.ntp = 0;
    mega<32, true, float><<<181, 256, 0, stream>>>(P);
  }
}